// Round 1
// baseline (1976.617 us; speedup 1.0000x reference)
//
#include <hip/hip_runtime.h>
#include <math.h>

#define NU 50000
#define NI 50000
#define DD 64
#define HHID 128
#define EE 500000
#define NEG_SLOPE 0.01f

// ---------------- el/er: per-node dot(feat_row, attn_vec), one wave per node
__global__ void dot_kernel(const float* __restrict__ feat, const float* __restrict__ vec,
                           float* __restrict__ out, int n) {
    int gid = blockIdx.x * blockDim.x + threadIdx.x;
    int wid = gid >> 6;
    int lane = threadIdx.x & 63;
    if (wid >= n) return;
    float v = feat[wid * DD + lane] * vec[lane];
#pragma unroll
    for (int off = 32; off > 0; off >>= 1) v += __shfl_down(v, off);
    if (lane == 0) out[wid] = v;
}

// ---------------- per-edge exp(leaky_relu(el+er)), accumulate denominator
__global__ void edge_exp_kernel(const int* __restrict__ src, const int* __restrict__ dst,
                                const float* __restrict__ el, const float* __restrict__ er,
                                float* __restrict__ ex, float* __restrict__ s, int e) {
    int k = blockIdx.x * blockDim.x + threadIdx.x;
    if (k >= e) return;
    float v = el[src[k]] + er[dst[k]];
    v = (v >= 0.f) ? v : NEG_SLOPE * v;
    float x = expf(v);
    ex[k] = x;
    atomicAdd(&s[dst[k]], x);
}

// ---------------- per-edge scatter: z[dst] += feat_src[src] * (ex/s[dst]); wave per edge
__global__ void edge_scatter_kernel(const int* __restrict__ src, const int* __restrict__ dst,
                                    const float* __restrict__ feat_src,
                                    const float* __restrict__ ex, const float* __restrict__ s,
                                    float* __restrict__ z, int e) {
    int k = (blockIdx.x * blockDim.x + threadIdx.x) >> 6;
    int lane = threadIdx.x & 63;
    if (k >= e) return;
    int sk = src[k], dk = dst[k];
    float a = ex[k] / s[dk];
    atomicAdd(&z[dk * (2 * DD) + lane], feat_src[sk * DD + lane] * a);
}

// ---------------- elementwise elu in place
__global__ void elu_kernel(float* __restrict__ z, int n) {
    int i = blockIdx.x * blockDim.x + threadIdx.x;
    if (i >= n) return;
    float v = z[i];
    z[i] = (v > 0.f) ? v : expm1f(v);
}

// ---------------- degree counting
__global__ void deg_kernel(const int* __restrict__ src, const int* __restrict__ dst,
                           float* __restrict__ dout, float* __restrict__ din, int e) {
    int k = blockIdx.x * blockDim.x + threadIdx.x;
    if (k >= e) return;
    atomicAdd(&dout[src[k]], 1.f);
    atomicAdd(&din[dst[k]], 1.f);
}

// ---------------- deg -> deg>0 ? deg^-0.5 : 1
__global__ void invsqrt_kernel(float* __restrict__ d, int n) {
    int i = blockIdx.x * blockDim.x + threadIdx.x;
    if (i >= n) return;
    float v = d[i];
    d[i] = (v > 0.f) ? (1.0f / sqrtf(v)) : 1.0f;
}

// ---------------- graphconv scatter: agg[dst] += feat[src]*no[src]; wave per edge
__global__ void gc_scatter_kernel(const int* __restrict__ src, const int* __restrict__ dst,
                                  const float* __restrict__ feat, const float* __restrict__ no,
                                  float* __restrict__ agg, int e) {
    int k = (blockIdx.x * blockDim.x + threadIdx.x) >> 6;
    int lane = threadIdx.x & 63;
    if (k >= e) return;
    int sk = src[k], dk = dst[k];
    atomicAdd(&agg[dk * (2 * DD) + lane], feat[sk * DD + lane] * no[sk]);
}

// ---------------- graphconv transform (in place): h[n] = elu((h[n]*ni[n]) @ W + b)
// block = 256 threads, 16 rows per block; W (64x64) staged in LDS
__global__ void gc_transform_kernel(float* __restrict__ h, const float* __restrict__ ni,
                                    const float* __restrict__ W, const float* __restrict__ b,
                                    int n) {
    __shared__ float sW[64 * 64];
    __shared__ float srow[16][64];
    int t = threadIdx.x;
    for (int i = t; i < 64 * 64; i += 256) sW[i] = W[i];
    int row0 = blockIdx.x * 16;
    for (int i = t; i < 16 * 64; i += 256) {
        int r = i >> 6, d = i & 63;
        int node = row0 + r;
        srow[r][d] = (node < n) ? h[node * 128 + d] * ni[node] : 0.f;
    }
    __syncthreads();
    int c = t & 63;
    int rbase = t >> 6;
    float bc = b[c];
#pragma unroll
    for (int rr = 0; rr < 4; rr++) {
        int r = rbase + rr * 4;
        float acc = 0.f;
#pragma unroll
        for (int k = 0; k < 64; k++) acc += srow[r][k] * sW[k * 64 + c];
        acc += bc;
        acc = (acc > 0.f) ? acc : expm1f(acc);
        int node = row0 + r;
        if (node < n) h[node * 128 + c] = acc;
    }
}

// ---------------- semantic attention w: wsum[m] += sum_n tanh(z[n,m] @ W1 + b1) @ w2
// block = 256 threads = 2 (node,metapath) pairs in flight; W1 (64x128) in LDS
__global__ void sem_att_kernel(const float* __restrict__ z, const float* __restrict__ W1,
                               const float* __restrict__ b1, const float* __restrict__ w2,
                               float* __restrict__ wsum, int n) {
    __shared__ float sW1[64 * HHID];
    __shared__ float sb1[HHID];
    __shared__ float sw2[HHID];
    __shared__ float zrow[2][64];
    __shared__ float lsum[2];
    int t = threadIdx.x;
    for (int i = t; i < 64 * HHID; i += 256) sW1[i] = W1[i];
    if (t < HHID) { sb1[t] = b1[t]; sw2[t] = w2[t]; }
    if (t < 2) lsum[t] = 0.f;
    __syncthreads();
    int sub = t >> 7;      // 0..1 (each = 2 waves)
    int hh = t & 127;      // hidden index
    int npairs = 2 * n;
    for (int p0 = blockIdx.x * 2; p0 < npairs; p0 += gridDim.x * 2) {
        int p = p0 + sub;
        int nn = p >> 1, mm = p & 1;
        __syncthreads();
        if (hh < 64) zrow[sub][hh] = (p < npairs) ? z[nn * 128 + mm * 64 + hh] : 0.f;
        __syncthreads();
        if (p < npairs) {
            float acc = 0.f;
#pragma unroll
            for (int k = 0; k < 64; k++) acc += zrow[sub][k] * sW1[k * HHID + hh];
            float val = tanhf(acc + sb1[hh]) * sw2[hh];
#pragma unroll
            for (int off = 32; off > 0; off >>= 1) val += __shfl_down(val, off);
            if ((t & 63) == 0) atomicAdd(&lsum[mm], val);
        }
    }
    __syncthreads();
    if (t < 2) atomicAdd(&wsum[t], lsum[t]);
}

// ---------------- final combine: out = sem(z)*beta + sem(h)*beta per node
__global__ void combine_kernel(const float* __restrict__ ZU, const float* __restrict__ ZI,
                               const float* __restrict__ HU, const float* __restrict__ HI,
                               const float* __restrict__ wsum, float* __restrict__ out) {
    int i = blockIdx.x * blockDim.x + threadIdx.x;
    const int total = (NU + NI) * DD;
    if (i >= total) return;
    int node = i >> 6;
    int d = i & 63;
    const float* zb; const float* hb;
    float wr0, wr1, wh0, wh1;
    int idx;
    if (node < NU) {
        zb = ZU; hb = HU; idx = node;
        wr0 = wsum[0]; wr1 = wsum[1]; wh0 = wsum[4]; wh1 = wsum[5];
    } else {
        zb = ZI; hb = HI; idx = node - NU;
        wr0 = wsum[2]; wr1 = wsum[3]; wh0 = wsum[6]; wh1 = wsum[7];
    }
    const float inv_n = 1.0f / 50000.0f;
    wr0 *= inv_n; wr1 *= inv_n; wh0 *= inv_n; wh1 *= inv_n;
    float m = fmaxf(wr0, wr1);
    float e0 = expf(wr0 - m), e1 = expf(wr1 - m);
    float br0 = e0 / (e0 + e1), br1 = e1 / (e0 + e1);
    m = fmaxf(wh0, wh1);
    e0 = expf(wh0 - m); e1 = expf(wh1 - m);
    float bh0 = e0 / (e0 + e1), bh1 = e1 / (e0 + e1);
    out[i] = zb[idx * 128 + d] * br0 + zb[idx * 128 + 64 + d] * br1
           + hb[idx * 128 + d] * bh0 + hb[idx * 128 + 64 + d] * bh1;
}

extern "C" void kernel_launch(void* const* d_in, const int* in_sizes, int n_in,
                              void* d_out, int out_size, void* d_ws, size_t ws_size,
                              hipStream_t stream) {
    const float* feat_user = (const float*)d_in[0];
    const float* feat_item = (const float*)d_in[1];
    const float* attn_l    = (const float*)d_in[2];
    const float* attn_r    = (const float*)d_in[3];
    const float* W_gc      = (const float*)d_in[4];
    const float* b_gc      = (const float*)d_in[5];
    const float* sa_rel_W1 = (const float*)d_in[6];
    const float* sa_rel_b1 = (const float*)d_in[7];
    const float* sa_rel_w2 = (const float*)d_in[8];
    const float* sa_u_W1   = (const float*)d_in[9];
    const float* sa_u_b1   = (const float*)d_in[10];
    const float* sa_u_w2   = (const float*)d_in[11];
    const float* sa_i_W1   = (const float*)d_in[12];
    const float* sa_i_b1   = (const float*)d_in[13];
    const float* sa_i_w2   = (const float*)d_in[14];
    const int* rel_u_src = (const int*)d_in[15];
    const int* rel_u_dst = (const int*)d_in[16];
    const int* rel_i_src = (const int*)d_in[17];
    const int* rel_i_dst = (const int*)d_in[18];
    const int* mp_u_src  = (const int*)d_in[19];
    const int* mp_u_dst  = (const int*)d_in[20];
    const int* mp_i_src  = (const int*)d_in[21];
    const int* mp_i_dst  = (const int*)d_in[22];

    // ---- workspace layout (floats) ----
    float* ws   = (float*)d_ws;
    float* ZU   = ws;                       // 50000*128
    float* ZI   = ZU + NU * 128;            // 50000*128
    float* HU   = ZI + NI * 128;            // 50000*128
    float* HI   = HU + NU * 128;            // 50000*128
    float* S    = HI + NI * 128;            // 4*50000 (GAT softmax denominators)
    float* DEG  = S + 4 * 50000;            // 8*50000 (per conv: out-deg then in-deg)
    float* WSUM = DEG + 8 * 50000;          // 8
    float* EL   = WSUM + 8;                 // 4*50000
    float* ER   = EL + 4 * 50000;           // 4*50000
    float* EX   = ER + 4 * 50000;           // 4*EE

    size_t zero_floats = (size_t)4 * 50000 * 128 + 4 * 50000 + 8 * 50000 + 8;
    hipMemsetAsync(ws, 0, zero_floats * sizeof(float), stream);

    // ---- GATs ----
    const float* gat_fsrc[4] = { feat_item, feat_item, feat_user, feat_user };
    const float* gat_fdst[4] = { feat_user, feat_user, feat_item, feat_item };
    const int*   gat_src[4]  = { rel_u_src, rel_u_src + EE, rel_i_src, rel_i_src + EE };
    const int*   gat_dst[4]  = { rel_u_dst, rel_u_dst + EE, rel_i_dst, rel_i_dst + EE };
    float*       gat_z[4]    = { ZU, ZU + 64, ZI, ZI + 64 };

    const int NB_DOT = (50000 * 64) / 256;          // 12500
    const int NB_E   = (EE + 255) / 256;            // 1954
    const int NB_ESC = (EE * 64) / 256;             // 125000

    for (int g = 0; g < 4; g++) {
        dot_kernel<<<NB_DOT, 256, 0, stream>>>(gat_fsrc[g], attn_l + g * DD, EL + g * 50000, 50000);
        dot_kernel<<<NB_DOT, 256, 0, stream>>>(gat_fdst[g], attn_r + g * DD, ER + g * 50000, 50000);
    }
    for (int g = 0; g < 4; g++) {
        edge_exp_kernel<<<NB_E, 256, 0, stream>>>(gat_src[g], gat_dst[g],
                                                  EL + g * 50000, ER + g * 50000,
                                                  EX + (size_t)g * EE, S + g * 50000, EE);
    }
    for (int g = 0; g < 4; g++) {
        edge_scatter_kernel<<<NB_ESC, 256, 0, stream>>>(gat_src[g], gat_dst[g], gat_fsrc[g],
                                                        EX + (size_t)g * EE, S + g * 50000,
                                                        gat_z[g], EE);
    }
    // elu over ZU and ZI (contiguous)
    elu_kernel<<<(2 * NU * 128) / 256, 256, 0, stream>>>(ZU, 2 * NU * 128);

    // ---- GraphConvs ----
    const int* gc_src[4]  = { mp_u_src, mp_u_src + EE, mp_i_src, mp_i_src + EE };
    const int* gc_dst[4]  = { mp_u_dst, mp_u_dst + EE, mp_i_dst, mp_i_dst + EE };
    const float* gc_feat[4] = { feat_user, feat_user, feat_item, feat_item };
    float* gc_h[4] = { HU, HU + 64, HI, HI + 64 };

    for (int c = 0; c < 4; c++) {
        deg_kernel<<<NB_E, 256, 0, stream>>>(gc_src[c], gc_dst[c],
                                             DEG + c * 100000, DEG + c * 100000 + 50000, EE);
    }
    invsqrt_kernel<<<(8 * 50000 + 255) / 256, 256, 0, stream>>>(DEG, 8 * 50000);
    for (int c = 0; c < 4; c++) {
        gc_scatter_kernel<<<NB_ESC, 256, 0, stream>>>(gc_src[c], gc_dst[c], gc_feat[c],
                                                      DEG + c * 100000, gc_h[c], EE);
    }
    for (int c = 0; c < 4; c++) {
        gc_transform_kernel<<<50000 / 16, 256, 0, stream>>>(gc_h[c], DEG + c * 100000 + 50000,
                                                            W_gc + c * 4096, b_gc + c * 64, 50000);
    }

    // ---- semantic attentions ----
    sem_att_kernel<<<1024, 256, 0, stream>>>(ZU, sa_rel_W1, sa_rel_b1, sa_rel_w2, WSUM + 0, 50000);
    sem_att_kernel<<<1024, 256, 0, stream>>>(ZI, sa_rel_W1, sa_rel_b1, sa_rel_w2, WSUM + 2, 50000);
    sem_att_kernel<<<1024, 256, 0, stream>>>(HU, sa_u_W1, sa_u_b1, sa_u_w2, WSUM + 4, 50000);
    sem_att_kernel<<<1024, 256, 0, stream>>>(HI, sa_i_W1, sa_i_b1, sa_i_w2, WSUM + 6, 50000);

    // ---- combine ----
    combine_kernel<<<((NU + NI) * DD) / 256, 256, 0, stream>>>(ZU, ZI, HU, HI, WSUM, (float*)d_out);
}

// Round 2
// 1515.638 us; speedup vs baseline: 1.3041x; 1.3041x over previous
//
#include <hip/hip_runtime.h>
#include <math.h>

#define NU 50000
#define NI 50000
#define NN 50000          // both sides are 50000
#define DD 64
#define HHID 128
#define EE 500000
#define NEG_SLOPE 0.01f

struct Ptr4c { const float* p[4]; };
struct Ptr4m { float*       p[4]; };
struct EdgeArgs { const int* src[8]; const int* dst[8]; };
struct GatArgs { const float* el[4]; const float* er[4]; const float* fsrc[4]; float* zout[4]; };
struct GcArgs  { const float* feat[4]; float* hout[4]; };

// ---------------- fused 4-way dot: out[j][v] = dot(feat[v], vec[j]); one wave per node
__global__ void dot4_kernel(const float* __restrict__ feat, Ptr4c vecs, Ptr4m outs, int n) {
    int gid = blockIdx.x * blockDim.x + threadIdx.x;
    int w = gid >> 6, lane = threadIdx.x & 63;
    if (w >= n) return;
    float f = feat[w * DD + lane];
#pragma unroll
    for (int j = 0; j < 4; j++) {
        float v = f * vecs.p[j][lane];
#pragma unroll
        for (int off = 32; off > 0; off >>= 1) v += __shfl_down(v, off);
        if (lane == 0) outs.p[j][w] = v;
    }
}

// ---------------- fused degree count over all 8 graphs (dst for all, src for GC graphs 4..7)
__global__ void deg_kernel(EdgeArgs a, int* __restrict__ deg_dst, int* __restrict__ deg_src_gc) {
    long long k = (long long)blockIdx.x * blockDim.x + threadIdx.x;
    if (k >= 8LL * EE) return;
    int g = (int)(k / EE);
    int e = (int)(k % EE);
    atomicAdd(&deg_dst[g * NN + a.dst[g][e]], 1);
    if (g >= 4) atomicAdd(&deg_src_gc[(g - 4) * NN + a.src[g][e]], 1);
}

// ---------------- degree -> norm (deg>0 ? deg^-0.5 : 1)
__global__ void norm_kernel(const int* __restrict__ deg_src_gc, const int* __restrict__ deg_dst,
                            float* __restrict__ NO, float* __restrict__ NIrm) {
    int i = blockIdx.x * blockDim.x + threadIdx.x;
    if (i < 4 * NN) {
        int d = deg_src_gc[i];
        NO[i] = (d > 0) ? (1.0f / sqrtf((float)d)) : 1.0f;
    } else if (i < 8 * NN) {
        int j = i - 4 * NN;
        int d = deg_dst[4 * NN + j];
        NIrm[j] = (d > 0) ? (1.0f / sqrtf((float)d)) : 1.0f;
    }
}

// ---------------- per-graph exclusive scan of deg -> cursor (start offsets); blockIdx = graph
__global__ void scan_kernel(const int* __restrict__ deg_dst, int* __restrict__ cursor) {
    __shared__ int part[1024];
    int g = blockIdx.x;
    const int* deg = deg_dst + g * NN;
    int* cur = cursor + g * NN;
    int t = threadIdx.x;
    const int CH = 49;                      // 49*1024 = 50176 >= 50000
    int lo = t * CH, hi = min(lo + CH, NN);
    int sum = 0;
    for (int i = lo; i < hi; i++) sum += deg[i];
    part[t] = sum;
    __syncthreads();
    for (int off = 1; off < 1024; off <<= 1) {
        int v = (t >= off) ? part[t - off] : 0;
        __syncthreads();
        part[t] += v;
        __syncthreads();
    }
    int run = (t > 0) ? part[t - 1] : 0;
    for (int i = lo; i < hi; i++) { cur[i] = run; run += deg[i]; }
}

// ---------------- fill buckets: bucket[g][pos] = src id; cursor advances to end-of-bucket
__global__ void fill_kernel(EdgeArgs a, int* __restrict__ cursor, int* __restrict__ bucket) {
    long long k = (long long)blockIdx.x * blockDim.x + threadIdx.x;
    if (k >= 8LL * EE) return;
    int g = (int)(k / EE);
    int e = (int)(k % EE);
    int pos = atomicAdd(&cursor[g * NN + a.dst[g][e]], 1);
    bucket[(size_t)g * EE + pos] = a.src[g][e];
}

// ---------------- GAT gather: one wave per (graph, dst node); inline softmax + elu
__global__ void gat_gather_kernel(GatArgs a, const int* __restrict__ deg_dst,
                                  const int* __restrict__ cursor, const int* __restrict__ bucket) {
    int gid = blockIdx.x * blockDim.x + threadIdx.x;
    int w = gid >> 6, lane = threadIdx.x & 63;
    if (w >= 4 * NN) return;
    int g = w / NN, v = w % NN;
    int dg = deg_dst[g * NN + v];
    int end = cursor[g * NN + v];
    int start = end - dg;
    const int* bk = bucket + (size_t)g * EE;
    const float* el = a.el[g];
    const float* fs = a.fsrc[g];
    float er_v = a.er[g][v];
    float acc = 0.f, s = 0.f;
    for (int base = 0; base < dg; base += 64) {
        int cnt = min(64, dg - base);
        int src_l = 0; float w_l = 0.f;
        if (lane < cnt) {
            src_l = bk[start + base + lane];
            float e = el[src_l] + er_v;
            e = (e >= 0.f) ? e : NEG_SLOPE * e;
            w_l = expf(e);
        }
        for (int j = 0; j < cnt; j++) {
            float wj = __shfl(w_l, j);
            int   sj = __shfl(src_l, j);
            acc += wj * fs[sj * DD + lane];
            s += wj;
        }
    }
    float o = 0.f;
    if (dg > 0) {
        o = acc / s;
        o = (o > 0.f) ? o : expm1f(o);
    }
    a.zout[g][(size_t)v * 128 + lane] = o;
}

// ---------------- GC gather + fused 64x64 transform; 16 nodes / 256-thread block
__global__ __launch_bounds__(256) void gc_kernel(GcArgs a, const float* __restrict__ W_gc,
                                                 const float* __restrict__ b_gc,
                                                 const float* __restrict__ NO,
                                                 const float* __restrict__ NIrm,
                                                 const int* __restrict__ deg_dst,
                                                 const int* __restrict__ cursor,
                                                 const int* __restrict__ bucket) {
    __shared__ float sW[64 * 64];
    __shared__ float srow[16][64];
    int g = blockIdx.x / 3125;          // 50000/16 = 3125 blocks per graph
    int nb = blockIdx.x % 3125;
    int t = threadIdx.x;
    const float* W = W_gc + g * 4096;
    for (int i = t; i < 4096; i += 256) sW[i] = W[i];
    int wid = t >> 6, lane = t & 63;
    const int* bk  = bucket + (size_t)(4 + g) * EE;
    const int* deg = deg_dst + (4 + g) * NN;
    const int* cur = cursor + (4 + g) * NN;
    const float* no = NO + g * NN;
    const float* ni = NIrm + g * NN;
    const float* feat = a.feat[g];
    for (int it = 0; it < 4; it++) {
        int r = wid * 4 + it;
        int v = nb * 16 + r;
        int dg = deg[v];
        int end = cur[v];
        int start = end - dg;
        float acc = 0.f;
        for (int base = 0; base < dg; base += 64) {
            int cnt = min(64, dg - base);
            int src_l = 0; float n_l = 0.f;
            if (lane < cnt) {
                src_l = bk[start + base + lane];
                n_l = no[src_l];
            }
            for (int j = 0; j < cnt; j++) {
                int   sj = __shfl(src_l, j);
                float nj = __shfl(n_l, j);
                acc += nj * feat[sj * DD + lane];
            }
        }
        srow[r][lane] = acc * ni[v];
    }
    __syncthreads();
    int c = lane;
    float bc = b_gc[g * 64 + c];
    float* hout = a.hout[g];
#pragma unroll
    for (int rr = 0; rr < 4; rr++) {
        int r = wid * 4 + rr;
        float accv = 0.f;
#pragma unroll
        for (int k = 0; k < 64; k++) accv += srow[r][k] * sW[k * 64 + c];
        accv += bc;
        accv = (accv > 0.f) ? accv : expm1f(accv);
        int v = nb * 16 + r;
        hout[(size_t)v * 128 + c] = accv;
    }
}

// ---------------- semantic attention w: wsum[m] += sum_n tanh(z[n,m] @ W1 + b1) @ w2
__global__ void sem_att_kernel(const float* __restrict__ z, const float* __restrict__ W1,
                               const float* __restrict__ b1, const float* __restrict__ w2,
                               float* __restrict__ wsum, int n) {
    __shared__ float sW1[64 * HHID];
    __shared__ float sb1[HHID];
    __shared__ float sw2[HHID];
    __shared__ float zrow[2][64];
    __shared__ float lsum[2];
    int t = threadIdx.x;
    for (int i = t; i < 64 * HHID; i += 256) sW1[i] = W1[i];
    if (t < HHID) { sb1[t] = b1[t]; sw2[t] = w2[t]; }
    if (t < 2) lsum[t] = 0.f;
    __syncthreads();
    int sub = t >> 7;
    int hh = t & 127;
    int npairs = 2 * n;
    for (int p0 = blockIdx.x * 2; p0 < npairs; p0 += gridDim.x * 2) {
        int p = p0 + sub;
        int nn2 = p >> 1, mm = p & 1;
        __syncthreads();
        if (hh < 64) zrow[sub][hh] = (p < npairs) ? z[(size_t)nn2 * 128 + mm * 64 + hh] : 0.f;
        __syncthreads();
        if (p < npairs) {
            float acc = 0.f;
#pragma unroll
            for (int k = 0; k < 64; k++) acc += zrow[sub][k] * sW1[k * HHID + hh];
            float val = tanhf(acc + sb1[hh]) * sw2[hh];
#pragma unroll
            for (int off = 32; off > 0; off >>= 1) val += __shfl_down(val, off);
            if ((t & 63) == 0) atomicAdd(&lsum[mm], val);
        }
    }
    __syncthreads();
    if (t < 2) atomicAdd(&wsum[t], lsum[t]);
}

// ---------------- final combine
__global__ void combine_kernel(const float* __restrict__ ZU, const float* __restrict__ ZI,
                               const float* __restrict__ HU, const float* __restrict__ HI,
                               const float* __restrict__ wsum, float* __restrict__ out) {
    int i = blockIdx.x * blockDim.x + threadIdx.x;
    const int total = (NU + NI) * DD;
    if (i >= total) return;
    int node = i >> 6;
    int d = i & 63;
    const float* zb; const float* hb;
    float wr0, wr1, wh0, wh1;
    int idx;
    if (node < NU) {
        zb = ZU; hb = HU; idx = node;
        wr0 = wsum[0]; wr1 = wsum[1]; wh0 = wsum[4]; wh1 = wsum[5];
    } else {
        zb = ZI; hb = HI; idx = node - NU;
        wr0 = wsum[2]; wr1 = wsum[3]; wh0 = wsum[6]; wh1 = wsum[7];
    }
    const float inv_n = 1.0f / 50000.0f;
    wr0 *= inv_n; wr1 *= inv_n; wh0 *= inv_n; wh1 *= inv_n;
    float m = fmaxf(wr0, wr1);
    float e0 = expf(wr0 - m), e1 = expf(wr1 - m);
    float br0 = e0 / (e0 + e1), br1 = e1 / (e0 + e1);
    m = fmaxf(wh0, wh1);
    e0 = expf(wh0 - m); e1 = expf(wh1 - m);
    float bh0 = e0 / (e0 + e1), bh1 = e1 / (e0 + e1);
    out[i] = zb[(size_t)idx * 128 + d] * br0 + zb[(size_t)idx * 128 + 64 + d] * br1
           + hb[(size_t)idx * 128 + d] * bh0 + hb[(size_t)idx * 128 + 64 + d] * bh1;
}

extern "C" void kernel_launch(void* const* d_in, const int* in_sizes, int n_in,
                              void* d_out, int out_size, void* d_ws, size_t ws_size,
                              hipStream_t stream) {
    const float* feat_user = (const float*)d_in[0];
    const float* feat_item = (const float*)d_in[1];
    const float* attn_l    = (const float*)d_in[2];
    const float* attn_r    = (const float*)d_in[3];
    const float* W_gc      = (const float*)d_in[4];
    const float* b_gc      = (const float*)d_in[5];
    const float* sa_rel_W1 = (const float*)d_in[6];
    const float* sa_rel_b1 = (const float*)d_in[7];
    const float* sa_rel_w2 = (const float*)d_in[8];
    const float* sa_u_W1   = (const float*)d_in[9];
    const float* sa_u_b1   = (const float*)d_in[10];
    const float* sa_u_w2   = (const float*)d_in[11];
    const float* sa_i_W1   = (const float*)d_in[12];
    const float* sa_i_b1   = (const float*)d_in[13];
    const float* sa_i_w2   = (const float*)d_in[14];
    const int* rel_u_src = (const int*)d_in[15];
    const int* rel_u_dst = (const int*)d_in[16];
    const int* rel_i_src = (const int*)d_in[17];
    const int* rel_i_dst = (const int*)d_in[18];
    const int* mp_u_src  = (const int*)d_in[19];
    const int* mp_u_dst  = (const int*)d_in[20];
    const int* mp_i_src  = (const int*)d_in[21];
    const int* mp_i_dst  = (const int*)d_in[22];

    // ---- workspace layout ----
    float* ws   = (float*)d_ws;
    float* ZU   = ws;                       // NU*128
    float* ZI   = ZU + NU * 128;            // NI*128
    float* HU   = ZI + NI * 128;            // NU*128
    float* HI   = HU + NU * 128;            // NI*128
    float* DI   = HI + NI * 128;            // 4*NI  (item dots: al0, al1, ar2, ar3)
    float* DU   = DI + 4 * NI;              // 4*NU  (user dots: al2, al3, ar0, ar1)
    float* NO   = DU + 4 * NU;              // 4*NN  (GC src out-norms)
    float* NIrm = NO + 4 * NN;              // 4*NN  (GC dst in-norms)
    int*   DEG_DST = (int*)(NIrm + 4 * NN); // 8*NN
    int*   DEG_SRC = DEG_DST + 8 * NN;      // 4*NN
    float* WSUM = (float*)(DEG_SRC + 4 * NN); // 8
    int*   CURSOR = (int*)(WSUM + 8);       // 8*NN
    int*   BUCKET = CURSOR + 8 * NN;        // 8*EE

    // zero DEG_DST + DEG_SRC + WSUM (contiguous)
    hipMemsetAsync(DEG_DST, 0, (size_t)(12 * NN) * sizeof(int) + 8 * sizeof(float), stream);

    // ---- fused dots ----
    Ptr4c vi = {{ attn_l + 0 * DD, attn_l + 1 * DD, attn_r + 2 * DD, attn_r + 3 * DD }};
    Ptr4m oi = {{ DI, DI + NI, DI + 2 * NI, DI + 3 * NI }};
    Ptr4c vu = {{ attn_l + 2 * DD, attn_l + 3 * DD, attn_r + 0 * DD, attn_r + 1 * DD }};
    Ptr4m ou = {{ DU, DU + NU, DU + 2 * NU, DU + 3 * NU }};
    dot4_kernel<<<(NN * 64) / 256, 256, 0, stream>>>(feat_item, vi, oi, NI);
    dot4_kernel<<<(NN * 64) / 256, 256, 0, stream>>>(feat_user, vu, ou, NU);

    // ---- CSR build over all 8 graphs ----
    EdgeArgs ea;
    ea.src[0] = rel_u_src;      ea.dst[0] = rel_u_dst;
    ea.src[1] = rel_u_src + EE; ea.dst[1] = rel_u_dst + EE;
    ea.src[2] = rel_i_src;      ea.dst[2] = rel_i_dst;
    ea.src[3] = rel_i_src + EE; ea.dst[3] = rel_i_dst + EE;
    ea.src[4] = mp_u_src;       ea.dst[4] = mp_u_dst;
    ea.src[5] = mp_u_src + EE;  ea.dst[5] = mp_u_dst + EE;
    ea.src[6] = mp_i_src;       ea.dst[6] = mp_i_dst;
    ea.src[7] = mp_i_src + EE;  ea.dst[7] = mp_i_dst + EE;

    const int NB_8E = (int)((8LL * EE) / 256);     // 15625
    deg_kernel<<<NB_8E, 256, 0, stream>>>(ea, DEG_DST, DEG_SRC);
    norm_kernel<<<(8 * NN + 255) / 256, 256, 0, stream>>>(DEG_SRC, DEG_DST, NO, NIrm);
    scan_kernel<<<8, 1024, 0, stream>>>(DEG_DST, CURSOR);
    fill_kernel<<<NB_8E, 256, 0, stream>>>(ea, CURSOR, BUCKET);

    // ---- GAT gather (4 graphs fused) ----
    GatArgs ga;
    ga.el[0] = DI;          ga.er[0] = DU + 2 * NU; ga.fsrc[0] = feat_item; ga.zout[0] = ZU;
    ga.el[1] = DI + NI;     ga.er[1] = DU + 3 * NU; ga.fsrc[1] = feat_item; ga.zout[1] = ZU + 64;
    ga.el[2] = DU;          ga.er[2] = DI + 2 * NI; ga.fsrc[2] = feat_user; ga.zout[2] = ZI;
    ga.el[3] = DU + NU;     ga.er[3] = DI + 3 * NI; ga.fsrc[3] = feat_user; ga.zout[3] = ZI + 64;
    gat_gather_kernel<<<(4 * NN * 64) / 256, 256, 0, stream>>>(ga, DEG_DST, CURSOR, BUCKET);

    // ---- GC gather + transform (4 graphs fused) ----
    GcArgs gc;
    gc.feat[0] = feat_user; gc.hout[0] = HU;
    gc.feat[1] = feat_user; gc.hout[1] = HU + 64;
    gc.feat[2] = feat_item; gc.hout[2] = HI;
    gc.feat[3] = feat_item; gc.hout[3] = HI + 64;
    gc_kernel<<<4 * 3125, 256, 0, stream>>>(gc, W_gc, b_gc, NO, NIrm, DEG_DST, CURSOR, BUCKET);

    // ---- semantic attentions ----
    sem_att_kernel<<<1024, 256, 0, stream>>>(ZU, sa_rel_W1, sa_rel_b1, sa_rel_w2, WSUM + 0, NU);
    sem_att_kernel<<<1024, 256, 0, stream>>>(ZI, sa_rel_W1, sa_rel_b1, sa_rel_w2, WSUM + 2, NI);
    sem_att_kernel<<<1024, 256, 0, stream>>>(HU, sa_u_W1, sa_u_b1, sa_u_w2, WSUM + 4, NU);
    sem_att_kernel<<<1024, 256, 0, stream>>>(HI, sa_i_W1, sa_i_b1, sa_i_w2, WSUM + 6, NI);

    // ---- combine ----
    combine_kernel<<<((NU + NI) * DD) / 256, 256, 0, stream>>>(ZU, ZI, HU, HI, WSUM, (float*)d_out);
}

// Round 3
// 952.541 us; speedup vs baseline: 2.0751x; 1.5912x over previous
//
#include <hip/hip_runtime.h>
#include <math.h>

#define NU 50000
#define NI 50000
#define NN 50000
#define DD 64
#define HHID 128
#define EE 500000
#define NEG_SLOPE 0.01f
#define NBKT 98            // coarse buckets of 512 nodes (dst>>9)
#define CAP 6144           // capacity per (graph,bucket) coarse region; mean 5120, sigma~71
#define TILE 4096
#define TPG 123            // tiles per graph = ceil(500000/4096)

struct Ptr4c { const float* p[4]; };
struct Ptr4m { float*       p[4]; };
struct EdgeArgs { const int* src[8]; const int* dst[8]; };
struct GatArgs { const float* el[4]; const float* er[4]; const float* fsrc[4]; float* zout[4]; };
struct GcArgs  { const float* feat[4]; float* hout[4]; };

// ---------------- fused 4-way dot: out[j][v] = dot(feat[v], vec[j]); one wave per node
__global__ void dot4_kernel(const float* __restrict__ feat, Ptr4c vecs, Ptr4m outs, int n) {
    int gid = blockIdx.x * blockDim.x + threadIdx.x;
    int w = gid >> 6, lane = threadIdx.x & 63;
    if (w >= n) return;
    float f = feat[w * DD + lane];
#pragma unroll
    for (int j = 0; j < 4; j++) {
        float v = f * vecs.p[j][lane];
#pragma unroll
        for (int off = 32; off > 0; off >>= 1) v += __shfl_down(v, off);
        if (lane == 0) outs.p[j][w] = v;
    }
}

// ---------------- pass 1: LDS counting-sort partition of edges by dst>>9 into coarse regions
__global__ __launch_bounds__(256) void part1_kernel(EdgeArgs a, int* __restrict__ ccnt,
                                                    int2* __restrict__ coarse) {
    __shared__ int bc_cnt[128], bc_scan[128], bc_start[128], bc_cur[128], bc_gbase[128];
    __shared__ int2 stage[TILE];
    __shared__ unsigned char sbkt[TILE];
    int t = threadIdx.x;
    int g = blockIdx.x / TPG;
    int tile = blockIdx.x % TPG;
    int e0 = tile * TILE;
    int tile_n = min(TILE, EE - e0);
    const int* gs = a.src[g];
    const int* gd = a.dst[g];
    if (t < 128) bc_cnt[t] = 0;
    __syncthreads();
    int2 pr[16]; int pb[16];
#pragma unroll
    for (int i = 0; i < 16; i++) {
        int pos = i * 256 + t;
        pb[i] = -1;
        if (pos < tile_n) {
            int e = e0 + pos;
            pr[i].x = gs[e]; pr[i].y = gd[e];
            pb[i] = pr[i].y >> 9;
            atomicAdd(&bc_cnt[pb[i]], 1);
        }
    }
    __syncthreads();
    if (t < 128) bc_scan[t] = bc_cnt[t];
    __syncthreads();
    for (int off = 1; off < 128; off <<= 1) {
        int v = 0;
        if (t < 128 && t >= off) v = bc_scan[t - off];
        __syncthreads();
        if (t < 128) bc_scan[t] += v;
        __syncthreads();
    }
    if (t < 128) {
        int st = bc_scan[t] - bc_cnt[t];
        bc_start[t] = st;
        bc_cur[t] = st;
        bc_gbase[t] = (t < NBKT && bc_cnt[t] > 0) ? atomicAdd(&ccnt[g * NBKT + t], bc_cnt[t]) : 0;
    }
    __syncthreads();
#pragma unroll
    for (int i = 0; i < 16; i++) {
        if (pb[i] >= 0) {
            int slot = atomicAdd(&bc_cur[pb[i]], 1);
            stage[slot] = pr[i];
            sbkt[slot] = (unsigned char)pb[i];
        }
    }
    __syncthreads();
    for (int j = t; j < tile_n; j += 256) {
        int b = sbkt[j];
        int2 p = stage[j];
        int pos = bc_gbase[b] + (j - bc_start[b]);
        if (pos < CAP) coarse[(size_t)(g * NBKT + b) * CAP + pos] = p;
    }
}

// ---------------- per-graph exclusive scan of coarse bucket counts
__global__ void scanb_kernel(const int* __restrict__ ccnt, int* __restrict__ bktbase) {
    __shared__ int s[128];
    int g = blockIdx.x, t = threadIdx.x;
    int orig = (t < NBKT) ? min(ccnt[g * NBKT + t], CAP) : 0;
    s[t] = orig;
    __syncthreads();
    for (int off = 1; off < 128; off <<= 1) {
        int v = (t >= off) ? s[t - off] : 0;
        __syncthreads();
        s[t] += v;
        __syncthreads();
    }
    if (t < NBKT) bktbase[g * NBKT + t] = s[t] - orig;
}

// ---------------- pass 2: per (graph,bucket) counting sort -> final CSR + row_start + deg + ni
__global__ __launch_bounds__(256) void part2_kernel(const int* __restrict__ ccnt,
                                                    const int* __restrict__ bktbase,
                                                    const int2* __restrict__ coarse,
                                                    int* __restrict__ bucket,
                                                    int* __restrict__ row_start,
                                                    int* __restrict__ dega,
                                                    float* __restrict__ nirm) {
    __shared__ int cnt5[512], off5[512], s2[256];
    __shared__ int ordered[CAP];
    int t = threadIdx.x;
    int g = blockIdx.x / NBKT;
    int b = blockIdx.x % NBKT;
    int n = min(ccnt[g * NBKT + b], CAP);
    int base = bktbase[g * NBKT + b];
    int node0 = b << 9;
    cnt5[t] = 0; cnt5[t + 256] = 0;
    __syncthreads();
    const int2* pairs = coarse + (size_t)(g * NBKT + b) * CAP;
    for (int i = t; i < n; i += 256) atomicAdd(&cnt5[pairs[i].y - node0], 1);
    __syncthreads();
    int pairsum = cnt5[2 * t] + cnt5[2 * t + 1];
    s2[t] = pairsum;
    __syncthreads();
    for (int off = 1; off < 256; off <<= 1) {
        int v = (t >= off) ? s2[t - off] : 0;
        __syncthreads();
        s2[t] += v;
        __syncthreads();
    }
    int ex = s2[t] - pairsum;
    off5[2 * t] = ex;
    off5[2 * t + 1] = ex + cnt5[2 * t];
    __syncthreads();
#pragma unroll
    for (int k = 0; k < 2; k++) {
        int j = 2 * t + k;
        int v = node0 + j;
        if (v < NN) {
            row_start[g * NN + v] = base + off5[j];
            int d = cnt5[j];
            dega[g * NN + v] = d;
            if (g >= 4) nirm[(g - 4) * NN + v] = (d > 0) ? rsqrtf((float)d) : 1.0f;
        }
    }
    __syncthreads();
    for (int i = t; i < n; i += 256) {
        int2 p = pairs[i];
        int slot = atomicAdd(&off5[p.y - node0], 1);
        ordered[slot] = p.x;
    }
    __syncthreads();
    for (int i = t; i < n; i += 256) bucket[(size_t)g * EE + base + i] = ordered[i];
}

// ---------------- src (out) degree for GC graphs
__global__ void srcdeg_kernel(EdgeArgs a, int* __restrict__ deg_src) {
    long long k = (long long)blockIdx.x * blockDim.x + threadIdx.x;
    if (k >= 4LL * EE) return;
    int g4 = (int)(k / EE);
    int e = (int)(k % EE);
    atomicAdd(&deg_src[g4 * NN + a.src[4 + g4][e]], 1);
}

__global__ void normno_kernel(const int* __restrict__ deg_src, float* __restrict__ no) {
    int i = blockIdx.x * blockDim.x + threadIdx.x;
    if (i >= 4 * NN) return;
    int d = deg_src[i];
    no[i] = (d > 0) ? rsqrtf((float)d) : 1.0f;
}

// ---------------- GAT gather: one wave per (graph,node); 4 edge-groups x 16 lanes, float4 rows
__global__ __launch_bounds__(256) void gat_gather_kernel(GatArgs a, const int* __restrict__ dega,
                                                         const int* __restrict__ row_start,
                                                         const int* __restrict__ bucket) {
    int gid = blockIdx.x * blockDim.x + threadIdx.x;
    int w = gid >> 6, lane = threadIdx.x & 63;
    if (w >= 4 * NN) return;
    int g = w / NN, v = w % NN;
    int dg = dega[g * NN + v];
    int start = row_start[g * NN + v];
    const int* bk = bucket + (size_t)g * EE;
    const float* el = a.el[g];
    const float* fs = a.fsrc[g];
    float er_v = a.er[g][v];
    int q = lane >> 4, lq = lane & 15;
    float4 acc = make_float4(0.f, 0.f, 0.f, 0.f);
    float s_l = 0.f;
    for (int base = 0; base < dg; base += 64) {
        int cnt = min(64, dg - base);
        int src_l = 0; float w_l = 0.f;
        if (lane < cnt) {
            src_l = bk[start + base + lane];
            float e = el[src_l] + er_v;
            e = (e >= 0.f) ? e : NEG_SLOPE * e;
            w_l = expf(e);
            s_l += w_l;
        }
        int jn = (cnt + 3) >> 2;
        for (int j = 0; j < jn; j++) {
            int lsrc = j * 4 + q;
            int sj = __shfl(src_l, lsrc);
            float wj = __shfl(w_l, lsrc);
            if (lsrc < cnt) {
                const float4 row = *(const float4*)(fs + (size_t)sj * DD + lq * 4);
                acc.x += wj * row.x; acc.y += wj * row.y;
                acc.z += wj * row.z; acc.w += wj * row.w;
            }
        }
    }
#pragma unroll
    for (int off = 16; off < 64; off <<= 1) {
        acc.x += __shfl_down(acc.x, off); acc.y += __shfl_down(acc.y, off);
        acc.z += __shfl_down(acc.z, off); acc.w += __shfl_down(acc.w, off);
    }
#pragma unroll
    for (int off = 32; off > 0; off >>= 1) s_l += __shfl_down(s_l, off);
    float s = __shfl(s_l, 0);
    if (q == 0) {
        float4 o = make_float4(0.f, 0.f, 0.f, 0.f);
        if (dg > 0) {
            float inv = 1.0f / s;
            o.x = acc.x * inv; o.y = acc.y * inv; o.z = acc.z * inv; o.w = acc.w * inv;
            o.x = (o.x > 0.f) ? o.x : expm1f(o.x);
            o.y = (o.y > 0.f) ? o.y : expm1f(o.y);
            o.z = (o.z > 0.f) ? o.z : expm1f(o.z);
            o.w = (o.w > 0.f) ? o.w : expm1f(o.w);
        }
        *(float4*)(a.zout[g] + (size_t)v * 128 + lq * 4) = o;
    }
}

// ---------------- GC gather (vectorized) + fused 64x64 transform; 16 nodes / block
__global__ __launch_bounds__(256) void gc_kernel(GcArgs a, const float* __restrict__ W_gc,
                                                 const float* __restrict__ b_gc,
                                                 const float* __restrict__ NO,
                                                 const float* __restrict__ NIrm,
                                                 const int* __restrict__ dega,
                                                 const int* __restrict__ row_start,
                                                 const int* __restrict__ bucket) {
    __shared__ float sW[64 * 64];
    __shared__ float srow[16][64];
    int g = blockIdx.x / 3125;
    int nb = blockIdx.x % 3125;
    int t = threadIdx.x;
    const float* W = W_gc + g * 4096;
    for (int i = t; i < 4096; i += 256) sW[i] = W[i];
    int wid = t >> 6, lane = t & 63;
    int q = lane >> 4, lq = lane & 15;
    const int* bk  = bucket + (size_t)(4 + g) * EE;
    const int* deg = dega + (4 + g) * NN;
    const int* row = row_start + (4 + g) * NN;
    const float* no = NO + g * NN;
    const float* ni = NIrm + g * NN;
    const float* feat = a.feat[g];
    for (int it = 0; it < 4; it++) {
        int r = wid * 4 + it;
        int v = nb * 16 + r;
        int dg = deg[v];
        int start = row[v];
        float4 acc = make_float4(0.f, 0.f, 0.f, 0.f);
        for (int base = 0; base < dg; base += 64) {
            int cnt = min(64, dg - base);
            int src_l = 0; float n_l = 0.f;
            if (lane < cnt) {
                src_l = bk[start + base + lane];
                n_l = no[src_l];
            }
            int jn = (cnt + 3) >> 2;
            for (int j = 0; j < jn; j++) {
                int lsrc = j * 4 + q;
                int sj = __shfl(src_l, lsrc);
                float nj = __shfl(n_l, lsrc);
                if (lsrc < cnt) {
                    const float4 rowv = *(const float4*)(feat + (size_t)sj * DD + lq * 4);
                    acc.x += nj * rowv.x; acc.y += nj * rowv.y;
                    acc.z += nj * rowv.z; acc.w += nj * rowv.w;
                }
            }
        }
#pragma unroll
        for (int off = 16; off < 64; off <<= 1) {
            acc.x += __shfl_down(acc.x, off); acc.y += __shfl_down(acc.y, off);
            acc.z += __shfl_down(acc.z, off); acc.w += __shfl_down(acc.w, off);
        }
        if (q == 0) {
            float niv = ni[v];
            *(float4*)(&srow[r][lq * 4]) = make_float4(acc.x * niv, acc.y * niv, acc.z * niv, acc.w * niv);
        }
    }
    __syncthreads();
    int c = lane;
    float bc = b_gc[g * 64 + c];
    float* hout = a.hout[g];
#pragma unroll
    for (int rr = 0; rr < 4; rr++) {
        int r = wid * 4 + rr;
        float accv = 0.f;
#pragma unroll
        for (int k = 0; k < 64; k++) accv += srow[r][k] * sW[k * 64 + c];
        accv += bc;
        accv = (accv > 0.f) ? accv : expm1f(accv);
        int v = nb * 16 + r;
        hout[(size_t)v * 128 + c] = accv;
    }
}

// ---------------- semantic attention w: wsum[m] += sum_n tanh(z[n,m] @ W1 + b1) @ w2
__global__ void sem_att_kernel(const float* __restrict__ z, const float* __restrict__ W1,
                               const float* __restrict__ b1, const float* __restrict__ w2,
                               float* __restrict__ wsum, int n) {
    __shared__ float sW1[64 * HHID];
    __shared__ float sb1[HHID];
    __shared__ float sw2[HHID];
    __shared__ float zrow[2][64];
    __shared__ float lsum[2];
    int t = threadIdx.x;
    for (int i = t; i < 64 * HHID; i += 256) sW1[i] = W1[i];
    if (t < HHID) { sb1[t] = b1[t]; sw2[t] = w2[t]; }
    if (t < 2) lsum[t] = 0.f;
    __syncthreads();
    int sub = t >> 7;
    int hh = t & 127;
    int npairs = 2 * n;
    for (int p0 = blockIdx.x * 2; p0 < npairs; p0 += gridDim.x * 2) {
        int p = p0 + sub;
        int nn2 = p >> 1, mm = p & 1;
        __syncthreads();
        if (hh < 64) zrow[sub][hh] = (p < npairs) ? z[(size_t)nn2 * 128 + mm * 64 + hh] : 0.f;
        __syncthreads();
        if (p < npairs) {
            float acc = 0.f;
#pragma unroll
            for (int k = 0; k < 64; k++) acc += zrow[sub][k] * sW1[k * HHID + hh];
            float val = tanhf(acc + sb1[hh]) * sw2[hh];
#pragma unroll
            for (int off = 32; off > 0; off >>= 1) val += __shfl_down(val, off);
            if ((t & 63) == 0) atomicAdd(&lsum[mm], val);
        }
    }
    __syncthreads();
    if (t < 2) atomicAdd(&wsum[t], lsum[t]);
}

// ---------------- final combine
__global__ void combine_kernel(const float* __restrict__ ZU, const float* __restrict__ ZI,
                               const float* __restrict__ HU, const float* __restrict__ HI,
                               const float* __restrict__ wsum, float* __restrict__ out) {
    int i = blockIdx.x * blockDim.x + threadIdx.x;
    const int total = (NU + NI) * DD;
    if (i >= total) return;
    int node = i >> 6;
    int d = i & 63;
    const float* zb; const float* hb;
    float wr0, wr1, wh0, wh1;
    int idx;
    if (node < NU) {
        zb = ZU; hb = HU; idx = node;
        wr0 = wsum[0]; wr1 = wsum[1]; wh0 = wsum[4]; wh1 = wsum[5];
    } else {
        zb = ZI; hb = HI; idx = node - NU;
        wr0 = wsum[2]; wr1 = wsum[3]; wh0 = wsum[6]; wh1 = wsum[7];
    }
    const float inv_n = 1.0f / 50000.0f;
    wr0 *= inv_n; wr1 *= inv_n; wh0 *= inv_n; wh1 *= inv_n;
    float m = fmaxf(wr0, wr1);
    float e0 = expf(wr0 - m), e1 = expf(wr1 - m);
    float br0 = e0 / (e0 + e1), br1 = e1 / (e0 + e1);
    m = fmaxf(wh0, wh1);
    e0 = expf(wh0 - m); e1 = expf(wh1 - m);
    float bh0 = e0 / (e0 + e1), bh1 = e1 / (e0 + e1);
    out[i] = zb[(size_t)idx * 128 + d] * br0 + zb[(size_t)idx * 128 + 64 + d] * br1
           + hb[(size_t)idx * 128 + d] * bh0 + hb[(size_t)idx * 128 + 64 + d] * bh1;
}

extern "C" void kernel_launch(void* const* d_in, const int* in_sizes, int n_in,
                              void* d_out, int out_size, void* d_ws, size_t ws_size,
                              hipStream_t stream) {
    const float* feat_user = (const float*)d_in[0];
    const float* feat_item = (const float*)d_in[1];
    const float* attn_l    = (const float*)d_in[2];
    const float* attn_r    = (const float*)d_in[3];
    const float* W_gc      = (const float*)d_in[4];
    const float* b_gc      = (const float*)d_in[5];
    const float* sa_rel_W1 = (const float*)d_in[6];
    const float* sa_rel_b1 = (const float*)d_in[7];
    const float* sa_rel_w2 = (const float*)d_in[8];
    const float* sa_u_W1   = (const float*)d_in[9];
    const float* sa_u_b1   = (const float*)d_in[10];
    const float* sa_u_w2   = (const float*)d_in[11];
    const float* sa_i_W1   = (const float*)d_in[12];
    const float* sa_i_b1   = (const float*)d_in[13];
    const float* sa_i_w2   = (const float*)d_in[14];
    const int* rel_u_src = (const int*)d_in[15];
    const int* rel_u_dst = (const int*)d_in[16];
    const int* rel_i_src = (const int*)d_in[17];
    const int* rel_i_dst = (const int*)d_in[18];
    const int* mp_u_src  = (const int*)d_in[19];
    const int* mp_u_dst  = (const int*)d_in[20];
    const int* mp_i_src  = (const int*)d_in[21];
    const int* mp_i_dst  = (const int*)d_in[22];

    // ---- workspace layout (floats) ----
    float* ws   = (float*)d_ws;
    float* ZU   = ws;                         // NU*128   (coarse regions alias here pre-gather)
    float* ZI   = ZU + NU * 128;
    float* HU   = ZI + NI * 128;
    float* HI   = HU + NU * 128;
    float* DI   = HI + NI * 128;              // 4*NN
    float* DU   = DI + 4 * NN;                // 4*NN
    float* NO   = DU + 4 * NN;                // 4*NN
    float* NIrm = NO + 4 * NN;                // 4*NN
    int*   ROW  = (int*)(NIrm + 4 * NN);      // 8*NN
    int*   DEGA = ROW + 8 * NN;               // 8*NN
    int*   BUCKET = DEGA + 8 * NN;            // 8*EE
    int*   BKTBASE = BUCKET + 8 * EE;         // 8*128 (padded)
    int*   CCNT = BKTBASE + 8 * 128;          // 8*128 (padded) -- zeroed
    int*   DEG_SRC = CCNT + 8 * 128;          // 4*NN          -- zeroed
    float* WSUM = (float*)(DEG_SRC + 4 * NN); // 8             -- zeroed
    int2*  COARSE = (int2*)ws;                // 8*98*CAP int2 = 38.5 MB, aliases ZU..HI

    hipMemsetAsync(CCNT, 0, (size_t)(8 * 128 + 4 * NN) * sizeof(int) + 8 * sizeof(float), stream);

    // ---- fused dots ----
    Ptr4c vi = {{ attn_l + 0 * DD, attn_l + 1 * DD, attn_r + 2 * DD, attn_r + 3 * DD }};
    Ptr4m oi = {{ DI, DI + NI, DI + 2 * NI, DI + 3 * NI }};
    Ptr4c vu = {{ attn_l + 2 * DD, attn_l + 3 * DD, attn_r + 0 * DD, attn_r + 1 * DD }};
    Ptr4m ou = {{ DU, DU + NU, DU + 2 * NU, DU + 3 * NU }};
    dot4_kernel<<<(NN * 64) / 256, 256, 0, stream>>>(feat_item, vi, oi, NI);
    dot4_kernel<<<(NN * 64) / 256, 256, 0, stream>>>(feat_user, vu, ou, NU);

    // ---- CSR build ----
    EdgeArgs ea;
    ea.src[0] = rel_u_src;      ea.dst[0] = rel_u_dst;
    ea.src[1] = rel_u_src + EE; ea.dst[1] = rel_u_dst + EE;
    ea.src[2] = rel_i_src;      ea.dst[2] = rel_i_dst;
    ea.src[3] = rel_i_src + EE; ea.dst[3] = rel_i_dst + EE;
    ea.src[4] = mp_u_src;       ea.dst[4] = mp_u_dst;
    ea.src[5] = mp_u_src + EE;  ea.dst[5] = mp_u_dst + EE;
    ea.src[6] = mp_i_src;       ea.dst[6] = mp_i_dst;
    ea.src[7] = mp_i_src + EE;  ea.dst[7] = mp_i_dst + EE;

    part1_kernel<<<8 * TPG, 256, 0, stream>>>(ea, CCNT, COARSE);
    scanb_kernel<<<8, 128, 0, stream>>>(CCNT, BKTBASE);
    part2_kernel<<<8 * NBKT, 256, 0, stream>>>(CCNT, BKTBASE, COARSE, BUCKET, ROW, DEGA, NIrm);
    srcdeg_kernel<<<(int)((4LL * EE + 255) / 256), 256, 0, stream>>>(ea, DEG_SRC);
    normno_kernel<<<(4 * NN + 255) / 256, 256, 0, stream>>>(DEG_SRC, NO);

    // ---- GAT gather (4 graphs fused) ----
    GatArgs ga;
    ga.el[0] = DI;          ga.er[0] = DU + 2 * NU; ga.fsrc[0] = feat_item; ga.zout[0] = ZU;
    ga.el[1] = DI + NI;     ga.er[1] = DU + 3 * NU; ga.fsrc[1] = feat_item; ga.zout[1] = ZU + 64;
    ga.el[2] = DU;          ga.er[2] = DI + 2 * NI; ga.fsrc[2] = feat_user; ga.zout[2] = ZI;
    ga.el[3] = DU + NU;     ga.er[3] = DI + 3 * NI; ga.fsrc[3] = feat_user; ga.zout[3] = ZI + 64;
    gat_gather_kernel<<<(4 * NN * 64) / 256, 256, 0, stream>>>(ga, DEGA, ROW, BUCKET);

    // ---- GC gather + transform (4 graphs fused) ----
    GcArgs gc;
    gc.feat[0] = feat_user; gc.hout[0] = HU;
    gc.feat[1] = feat_user; gc.hout[1] = HU + 64;
    gc.feat[2] = feat_item; gc.hout[2] = HI;
    gc.feat[3] = feat_item; gc.hout[3] = HI + 64;
    gc_kernel<<<4 * 3125, 256, 0, stream>>>(gc, W_gc, b_gc, NO, NIrm, DEGA, ROW, BUCKET);

    // ---- semantic attentions ----
    sem_att_kernel<<<1024, 256, 0, stream>>>(ZU, sa_rel_W1, sa_rel_b1, sa_rel_w2, WSUM + 0, NU);
    sem_att_kernel<<<1024, 256, 0, stream>>>(ZI, sa_rel_W1, sa_rel_b1, sa_rel_w2, WSUM + 2, NI);
    sem_att_kernel<<<1024, 256, 0, stream>>>(HU, sa_u_W1, sa_u_b1, sa_u_w2, WSUM + 4, NU);
    sem_att_kernel<<<1024, 256, 0, stream>>>(HI, sa_i_W1, sa_i_b1, sa_i_w2, WSUM + 6, NI);

    // ---- combine ----
    combine_kernel<<<((NU + NI) * DD) / 256, 256, 0, stream>>>(ZU, ZI, HU, HI, WSUM, (float*)d_out);
}

// Round 4
// 925.325 us; speedup vs baseline: 2.1361x; 1.0294x over previous
//
#include <hip/hip_runtime.h>
#include <math.h>

#define NU 50000
#define NI 50000
#define NN 50000
#define DD 64
#define HHID 128
#define EE 500000
#define NEG_SLOPE 0.01f
#define NBKT 98            // coarse buckets of 512 nodes (dst>>9)
#define CAP 6144           // capacity per (graph,bucket) coarse region; mean 5120, sigma~71
#define TILE 4096
#define TPG 123            // tiles per graph = ceil(500000/4096)

typedef _Float16 half_t;
union H4 { uint2 u; half_t h[4]; };

struct Ptr4c { const float* p[4]; };
struct Ptr4m { float*       p[4]; };
struct EdgeArgs { const int* src[8]; const int* dst[8]; };
struct GatArgs { const float* el[4]; const float* er[4]; const half_t* fsrc[4]; half_t* zout[4]; };
struct GcArgs  { const half_t* feat[4]; half_t* hout[4]; };

// ---------------- convert both fp32 feature tables to fp16
__global__ void cvt_kernel(const float* __restrict__ fu, const float* __restrict__ fi,
                           half_t* __restrict__ hu, half_t* __restrict__ hi_) {
    int i = blockIdx.x * blockDim.x + threadIdx.x;
    const int quarter = NN * DD / 4;            // 800000 float4s per table
    const float4* srcp; uint2* dstp; int j;
    if (i < quarter) { srcp = (const float4*)fu; dstp = (uint2*)hu; j = i; }
    else { j = i - quarter; if (j >= quarter) return; srcp = (const float4*)fi; dstp = (uint2*)hi_; }
    float4 v = srcp[j];
    H4 o;
    o.h[0] = (half_t)v.x; o.h[1] = (half_t)v.y; o.h[2] = (half_t)v.z; o.h[3] = (half_t)v.w;
    dstp[j] = o.u;
}

// ---------------- fused 4-way dot: out[j][v] = dot(feat[v], vec[j]); one wave per node
__global__ void dot4_kernel(const float* __restrict__ feat, Ptr4c vecs, Ptr4m outs, int n) {
    int gid = blockIdx.x * blockDim.x + threadIdx.x;
    int w = gid >> 6, lane = threadIdx.x & 63;
    if (w >= n) return;
    float f = feat[w * DD + lane];
#pragma unroll
    for (int j = 0; j < 4; j++) {
        float v = f * vecs.p[j][lane];
#pragma unroll
        for (int off = 32; off > 0; off >>= 1) v += __shfl_down(v, off);
        if (lane == 0) outs.p[j][w] = v;
    }
}

// ---------------- pass 1: LDS counting-sort partition by dst>>9; packed record src|(dst&511)<<16
// also accumulates GC src out-degrees (g>=4)
__global__ __launch_bounds__(256) void part1_kernel(EdgeArgs a, int* __restrict__ ccnt,
                                                    int* __restrict__ coarse,
                                                    int* __restrict__ deg_src) {
    __shared__ int bc_cnt[128], bc_scan[128], bc_start[128], bc_cur[128], bc_gbase[128];
    __shared__ int stage[TILE];
    __shared__ unsigned char sbkt[TILE];
    int t = threadIdx.x;
    int g = blockIdx.x / TPG;
    int tile = blockIdx.x % TPG;
    int e0 = tile * TILE;
    int tile_n = min(TILE, EE - e0);
    const int* gs = a.src[g];
    const int* gd = a.dst[g];
    if (t < 128) bc_cnt[t] = 0;
    __syncthreads();
    int pw[16]; int pb[16];
#pragma unroll
    for (int i = 0; i < 16; i++) {
        int pos = i * 256 + t;
        pb[i] = -1;
        if (pos < tile_n) {
            int e = e0 + pos;
            int s = gs[e], d = gd[e];
            pw[i] = s | ((d & 511) << 16);
            pb[i] = d >> 9;
            atomicAdd(&bc_cnt[pb[i]], 1);
            if (g >= 4) atomicAdd(&deg_src[(g - 4) * NN + s], 1);
        }
    }
    __syncthreads();
    if (t < 128) bc_scan[t] = bc_cnt[t];
    __syncthreads();
    for (int off = 1; off < 128; off <<= 1) {
        int v = 0;
        if (t < 128 && t >= off) v = bc_scan[t - off];
        __syncthreads();
        if (t < 128) bc_scan[t] += v;
        __syncthreads();
    }
    if (t < 128) {
        int st = bc_scan[t] - bc_cnt[t];
        bc_start[t] = st;
        bc_cur[t] = st;
        bc_gbase[t] = (t < NBKT && bc_cnt[t] > 0) ? atomicAdd(&ccnt[g * NBKT + t], bc_cnt[t]) : 0;
    }
    __syncthreads();
#pragma unroll
    for (int i = 0; i < 16; i++) {
        if (pb[i] >= 0) {
            int slot = atomicAdd(&bc_cur[pb[i]], 1);
            stage[slot] = pw[i];
            sbkt[slot] = (unsigned char)pb[i];
        }
    }
    __syncthreads();
    for (int j = t; j < tile_n; j += 256) {
        int b = sbkt[j];
        int p = stage[j];
        int pos = bc_gbase[b] + (j - bc_start[b]);
        if (pos < CAP) coarse[(size_t)(g * NBKT + b) * CAP + pos] = p;
    }
}

// ---------------- per-graph exclusive scan of coarse bucket counts
__global__ void scanb_kernel(const int* __restrict__ ccnt, int* __restrict__ bktbase) {
    __shared__ int s[128];
    int g = blockIdx.x, t = threadIdx.x;
    int orig = (t < NBKT) ? min(ccnt[g * NBKT + t], CAP) : 0;
    s[t] = orig;
    __syncthreads();
    for (int off = 1; off < 128; off <<= 1) {
        int v = (t >= off) ? s[t - off] : 0;
        __syncthreads();
        s[t] += v;
        __syncthreads();
    }
    if (t < NBKT) bktbase[g * NBKT + t] = s[t] - orig;
}

// ---------------- pass 2: per (graph,bucket) counting sort -> final CSR + row_start + deg + ni
__global__ __launch_bounds__(256) void part2_kernel(const int* __restrict__ ccnt,
                                                    const int* __restrict__ bktbase,
                                                    const int* __restrict__ coarse,
                                                    int* __restrict__ bucket,
                                                    int* __restrict__ row_start,
                                                    int* __restrict__ dega,
                                                    float* __restrict__ nirm) {
    __shared__ int cnt5[512], off5[512], s2[256];
    __shared__ int spairs[CAP];
    __shared__ int ordered[CAP];
    int t = threadIdx.x;
    int g = blockIdx.x / NBKT;
    int b = blockIdx.x % NBKT;
    int n = min(ccnt[g * NBKT + b], CAP);
    int base = bktbase[g * NBKT + b];
    int node0 = b << 9;
    cnt5[t] = 0; cnt5[t + 256] = 0;
    __syncthreads();
    const int* pairs = coarse + (size_t)(g * NBKT + b) * CAP;
    for (int i = t; i < n; i += 256) {
        int p = pairs[i];
        spairs[i] = p;
        atomicAdd(&cnt5[p >> 16], 1);
    }
    __syncthreads();
    int pairsum = cnt5[2 * t] + cnt5[2 * t + 1];
    s2[t] = pairsum;
    __syncthreads();
    for (int off = 1; off < 256; off <<= 1) {
        int v = (t >= off) ? s2[t - off] : 0;
        __syncthreads();
        s2[t] += v;
        __syncthreads();
    }
    int ex = s2[t] - pairsum;
    off5[2 * t] = ex;
    off5[2 * t + 1] = ex + cnt5[2 * t];
    __syncthreads();
#pragma unroll
    for (int k = 0; k < 2; k++) {
        int j = 2 * t + k;
        int v = node0 + j;
        if (v < NN) {
            row_start[g * NN + v] = base + off5[j];
            int d = cnt5[j];
            dega[g * NN + v] = d;
            if (g >= 4) nirm[(g - 4) * NN + v] = (d > 0) ? rsqrtf((float)d) : 1.0f;
        }
    }
    __syncthreads();
    for (int i = t; i < n; i += 256) {
        int p = spairs[i];
        int slot = atomicAdd(&off5[p >> 16], 1);
        ordered[slot] = p & 0xFFFF;
    }
    __syncthreads();
    for (int i = t; i < n; i += 256) bucket[(size_t)g * EE + base + i] = ordered[i];
}

__global__ void normno_kernel(const int* __restrict__ deg_src, float* __restrict__ no) {
    int i = blockIdx.x * blockDim.x + threadIdx.x;
    if (i >= 4 * NN) return;
    int d = deg_src[i];
    no[i] = (d > 0) ? rsqrtf((float)d) : 1.0f;
}

// ---------------- GAT gather: one wave per (graph,node); 4 edge-groups x 16 lanes, fp16 rows
__global__ __launch_bounds__(256) void gat_gather_kernel(GatArgs a, const int* __restrict__ dega,
                                                         const int* __restrict__ row_start,
                                                         const int* __restrict__ bucket) {
    int gid = blockIdx.x * blockDim.x + threadIdx.x;
    int w = gid >> 6, lane = threadIdx.x & 63;
    if (w >= 4 * NN) return;
    int g = w / NN, v = w % NN;
    int dg = dega[g * NN + v];
    int start = row_start[g * NN + v];
    const int* bk = bucket + (size_t)g * EE;
    const float* el = a.el[g];
    const half_t* fs = a.fsrc[g];
    float er_v = a.er[g][v];
    int q = lane >> 4, lq = lane & 15;
    float4 acc = make_float4(0.f, 0.f, 0.f, 0.f);
    float s_l = 0.f;
    for (int base = 0; base < dg; base += 64) {
        int cnt = min(64, dg - base);
        int src_l = 0; float w_l = 0.f;
        if (lane < cnt) {
            src_l = bk[start + base + lane];
            float e = el[src_l] + er_v;
            e = (e >= 0.f) ? e : NEG_SLOPE * e;
            w_l = expf(e);
            s_l += w_l;
        }
        int jn = (cnt + 3) >> 2;
        for (int j = 0; j < jn; j++) {
            int lsrc = j * 4 + q;
            int sj = __shfl(src_l, lsrc);
            float wj = __shfl(w_l, lsrc);
            if (lsrc < cnt) {
                H4 r;
                r.u = *(const uint2*)(fs + (size_t)sj * DD + lq * 4);
                acc.x += wj * (float)r.h[0]; acc.y += wj * (float)r.h[1];
                acc.z += wj * (float)r.h[2]; acc.w += wj * (float)r.h[3];
            }
        }
    }
#pragma unroll
    for (int off = 16; off < 64; off <<= 1) {
        acc.x += __shfl_down(acc.x, off); acc.y += __shfl_down(acc.y, off);
        acc.z += __shfl_down(acc.z, off); acc.w += __shfl_down(acc.w, off);
    }
#pragma unroll
    for (int off = 32; off > 0; off >>= 1) s_l += __shfl_down(s_l, off);
    float s = __shfl(s_l, 0);
    if (q == 0) {
        float ox = 0.f, oy = 0.f, oz = 0.f, ow = 0.f;
        if (dg > 0) {
            float inv = 1.0f / s;
            ox = acc.x * inv; oy = acc.y * inv; oz = acc.z * inv; ow = acc.w * inv;
            ox = (ox > 0.f) ? ox : expm1f(ox);
            oy = (oy > 0.f) ? oy : expm1f(oy);
            oz = (oz > 0.f) ? oz : expm1f(oz);
            ow = (ow > 0.f) ? ow : expm1f(ow);
        }
        H4 o;
        o.h[0] = (half_t)ox; o.h[1] = (half_t)oy; o.h[2] = (half_t)oz; o.h[3] = (half_t)ow;
        *(uint2*)(a.zout[g] + (size_t)v * 128 + lq * 4) = o.u;
    }
}

// ---------------- GC gather (fp16 rows) + fused 64x64 transform; 16 nodes / block
__global__ __launch_bounds__(256) void gc_kernel(GcArgs a, const float* __restrict__ W_gc,
                                                 const float* __restrict__ b_gc,
                                                 const float* __restrict__ NO,
                                                 const float* __restrict__ NIrm,
                                                 const int* __restrict__ dega,
                                                 const int* __restrict__ row_start,
                                                 const int* __restrict__ bucket) {
    __shared__ float sW[64 * 64];
    __shared__ float srow[16][64];
    int g = blockIdx.x / 3125;
    int nb = blockIdx.x % 3125;
    int t = threadIdx.x;
    const float* W = W_gc + g * 4096;
    for (int i = t; i < 4096; i += 256) sW[i] = W[i];
    int wid = t >> 6, lane = t & 63;
    int q = lane >> 4, lq = lane & 15;
    const int* bk  = bucket + (size_t)(4 + g) * EE;
    const int* deg = dega + (4 + g) * NN;
    const int* row = row_start + (4 + g) * NN;
    const float* no = NO + g * NN;
    const float* ni = NIrm + g * NN;
    const half_t* feat = a.feat[g];
    for (int it = 0; it < 4; it++) {
        int r = wid * 4 + it;
        int v = nb * 16 + r;
        int dg = deg[v];
        int start = row[v];
        float4 acc = make_float4(0.f, 0.f, 0.f, 0.f);
        for (int base = 0; base < dg; base += 64) {
            int cnt = min(64, dg - base);
            int src_l = 0; float n_l = 0.f;
            if (lane < cnt) {
                src_l = bk[start + base + lane];
                n_l = no[src_l];
            }
            int jn = (cnt + 3) >> 2;
            for (int j = 0; j < jn; j++) {
                int lsrc = j * 4 + q;
                int sj = __shfl(src_l, lsrc);
                float nj = __shfl(n_l, lsrc);
                if (lsrc < cnt) {
                    H4 r4;
                    r4.u = *(const uint2*)(feat + (size_t)sj * DD + lq * 4);
                    acc.x += nj * (float)r4.h[0]; acc.y += nj * (float)r4.h[1];
                    acc.z += nj * (float)r4.h[2]; acc.w += nj * (float)r4.h[3];
                }
            }
        }
#pragma unroll
        for (int off = 16; off < 64; off <<= 1) {
            acc.x += __shfl_down(acc.x, off); acc.y += __shfl_down(acc.y, off);
            acc.z += __shfl_down(acc.z, off); acc.w += __shfl_down(acc.w, off);
        }
        if (q == 0) {
            float niv = ni[v];
            *(float4*)(&srow[r][lq * 4]) = make_float4(acc.x * niv, acc.y * niv, acc.z * niv, acc.w * niv);
        }
    }
    __syncthreads();
    int c = lane;
    float bc = b_gc[g * 64 + c];
    half_t* hout = a.hout[g];
#pragma unroll
    for (int rr = 0; rr < 4; rr++) {
        int r = wid * 4 + rr;
        float accv = 0.f;
#pragma unroll
        for (int k = 0; k < 64; k++) accv += srow[r][k] * sW[k * 64 + c];
        accv += bc;
        accv = (accv > 0.f) ? accv : expm1f(accv);
        int v = nb * 16 + r;
        hout[(size_t)v * 128 + c] = (half_t)accv;
    }
}

// ---------------- semantic attention w: wsum[m] += sum_n tanh(z[n,m] @ W1 + b1) @ w2
__global__ void sem_att_kernel(const half_t* __restrict__ z, const float* __restrict__ W1,
                               const float* __restrict__ b1, const float* __restrict__ w2,
                               float* __restrict__ wsum, int n) {
    __shared__ float sW1[64 * HHID];
    __shared__ float sb1[HHID];
    __shared__ float sw2[HHID];
    __shared__ float zrow[2][64];
    __shared__ float lsum[2];
    int t = threadIdx.x;
    for (int i = t; i < 64 * HHID; i += 256) sW1[i] = W1[i];
    if (t < HHID) { sb1[t] = b1[t]; sw2[t] = w2[t]; }
    if (t < 2) lsum[t] = 0.f;
    __syncthreads();
    int sub = t >> 7;
    int hh = t & 127;
    int npairs = 2 * n;
    for (int p0 = blockIdx.x * 2; p0 < npairs; p0 += gridDim.x * 2) {
        int p = p0 + sub;
        int nn2 = p >> 1, mm = p & 1;
        __syncthreads();
        if (hh < 64) zrow[sub][hh] = (p < npairs) ? (float)z[(size_t)nn2 * 128 + mm * 64 + hh] : 0.f;
        __syncthreads();
        if (p < npairs) {
            float acc = 0.f;
#pragma unroll
            for (int k = 0; k < 64; k++) acc += zrow[sub][k] * sW1[k * HHID + hh];
            float val = tanhf(acc + sb1[hh]) * sw2[hh];
#pragma unroll
            for (int off = 32; off > 0; off >>= 1) val += __shfl_down(val, off);
            if ((t & 63) == 0) atomicAdd(&lsum[mm], val);
        }
    }
    __syncthreads();
    if (t < 2) atomicAdd(&wsum[t], lsum[t]);
}

// ---------------- final combine
__global__ void combine_kernel(const half_t* __restrict__ ZU, const half_t* __restrict__ ZI,
                               const half_t* __restrict__ HU, const half_t* __restrict__ HI,
                               const float* __restrict__ wsum, float* __restrict__ out) {
    int i = blockIdx.x * blockDim.x + threadIdx.x;
    const int total = (NU + NI) * DD;
    if (i >= total) return;
    int node = i >> 6;
    int d = i & 63;
    const half_t* zb; const half_t* hb;
    float wr0, wr1, wh0, wh1;
    int idx;
    if (node < NU) {
        zb = ZU; hb = HU; idx = node;
        wr0 = wsum[0]; wr1 = wsum[1]; wh0 = wsum[4]; wh1 = wsum[5];
    } else {
        zb = ZI; hb = HI; idx = node - NU;
        wr0 = wsum[2]; wr1 = wsum[3]; wh0 = wsum[6]; wh1 = wsum[7];
    }
    const float inv_n = 1.0f / 50000.0f;
    wr0 *= inv_n; wr1 *= inv_n; wh0 *= inv_n; wh1 *= inv_n;
    float m = fmaxf(wr0, wr1);
    float e0 = expf(wr0 - m), e1 = expf(wr1 - m);
    float br0 = e0 / (e0 + e1), br1 = e1 / (e0 + e1);
    m = fmaxf(wh0, wh1);
    e0 = expf(wh0 - m); e1 = expf(wh1 - m);
    float bh0 = e0 / (e0 + e1), bh1 = e1 / (e0 + e1);
    out[i] = (float)zb[(size_t)idx * 128 + d] * br0 + (float)zb[(size_t)idx * 128 + 64 + d] * br1
           + (float)hb[(size_t)idx * 128 + d] * bh0 + (float)hb[(size_t)idx * 128 + 64 + d] * bh1;
}

extern "C" void kernel_launch(void* const* d_in, const int* in_sizes, int n_in,
                              void* d_out, int out_size, void* d_ws, size_t ws_size,
                              hipStream_t stream) {
    const float* feat_user = (const float*)d_in[0];
    const float* feat_item = (const float*)d_in[1];
    const float* attn_l    = (const float*)d_in[2];
    const float* attn_r    = (const float*)d_in[3];
    const float* W_gc      = (const float*)d_in[4];
    const float* b_gc      = (const float*)d_in[5];
    const float* sa_rel_W1 = (const float*)d_in[6];
    const float* sa_rel_b1 = (const float*)d_in[7];
    const float* sa_rel_w2 = (const float*)d_in[8];
    const float* sa_u_W1   = (const float*)d_in[9];
    const float* sa_u_b1   = (const float*)d_in[10];
    const float* sa_u_w2   = (const float*)d_in[11];
    const float* sa_i_W1   = (const float*)d_in[12];
    const float* sa_i_b1   = (const float*)d_in[13];
    const float* sa_i_w2   = (const float*)d_in[14];
    const int* rel_u_src = (const int*)d_in[15];
    const int* rel_u_dst = (const int*)d_in[16];
    const int* rel_i_src = (const int*)d_in[17];
    const int* rel_i_dst = (const int*)d_in[18];
    const int* mp_u_src  = (const int*)d_in[19];
    const int* mp_u_dst  = (const int*)d_in[20];
    const int* mp_i_src  = (const int*)d_in[21];
    const int* mp_i_dst  = (const int*)d_in[22];

    // ---- workspace layout ----
    half_t* ZU   = (half_t*)d_ws;             // NN*128 fp16 = 12.8 MB
    half_t* ZI   = ZU + NN * 128;
    half_t* HU   = ZI + NN * 128;
    half_t* HI   = HU + NN * 128;
    half_t* FBU  = HI + NN * 128;             // fp16 feat_user, NN*64
    half_t* FBI  = FBU + NN * 64;             // fp16 feat_item, NN*64
    float*  DI   = (float*)(FBI + NN * 64);   // 4*NN
    float*  DU   = DI + 4 * NN;               // 4*NN
    float*  NO   = DU + 4 * NN;               // 4*NN
    float*  NIrm = NO + 4 * NN;               // 4*NN
    int*    ROW  = (int*)(NIrm + 4 * NN);     // 8*NN
    int*    DEGA = ROW + 8 * NN;              // 8*NN
    int*    BUCKET = DEGA + 8 * NN;           // 8*EE
    int*    BKTBASE = BUCKET + 8 * EE;        // 8*128
    int*    CCNT = BKTBASE + 8 * 128;         // 8*128  -- zeroed
    int*    DEG_SRC = CCNT + 8 * 128;         // 4*NN   -- zeroed
    float*  WSUM = (float*)(DEG_SRC + 4 * NN);// 8      -- zeroed
    int*    COARSE = (int*)d_ws;              // 8*98*CAP ints = 19.3 MB, aliases ZU..; dead before gathers

    hipMemsetAsync(CCNT, 0, (size_t)(8 * 128 + 4 * NN) * sizeof(int) + 8 * sizeof(float), stream);

    // ---- fp16 tables + fused dots ----
    cvt_kernel<<<(2 * NN * DD / 4 + 255) / 256, 256, 0, stream>>>(feat_user, feat_item, FBU, FBI);
    Ptr4c vi = {{ attn_l + 0 * DD, attn_l + 1 * DD, attn_r + 2 * DD, attn_r + 3 * DD }};
    Ptr4m oi = {{ DI, DI + NI, DI + 2 * NI, DI + 3 * NI }};
    Ptr4c vu = {{ attn_l + 2 * DD, attn_l + 3 * DD, attn_r + 0 * DD, attn_r + 1 * DD }};
    Ptr4m ou = {{ DU, DU + NU, DU + 2 * NU, DU + 3 * NU }};
    dot4_kernel<<<(NN * 64) / 256, 256, 0, stream>>>(feat_item, vi, oi, NI);
    dot4_kernel<<<(NN * 64) / 256, 256, 0, stream>>>(feat_user, vu, ou, NU);

    // ---- CSR build ----
    EdgeArgs ea;
    ea.src[0] = rel_u_src;      ea.dst[0] = rel_u_dst;
    ea.src[1] = rel_u_src + EE; ea.dst[1] = rel_u_dst + EE;
    ea.src[2] = rel_i_src;      ea.dst[2] = rel_i_dst;
    ea.src[3] = rel_i_src + EE; ea.dst[3] = rel_i_dst + EE;
    ea.src[4] = mp_u_src;       ea.dst[4] = mp_u_dst;
    ea.src[5] = mp_u_src + EE;  ea.dst[5] = mp_u_dst + EE;
    ea.src[6] = mp_i_src;       ea.dst[6] = mp_i_dst;
    ea.src[7] = mp_i_src + EE;  ea.dst[7] = mp_i_dst + EE;

    part1_kernel<<<8 * TPG, 256, 0, stream>>>(ea, CCNT, COARSE, DEG_SRC);
    scanb_kernel<<<8, 128, 0, stream>>>(CCNT, BKTBASE);
    part2_kernel<<<8 * NBKT, 256, 0, stream>>>(CCNT, BKTBASE, COARSE, BUCKET, ROW, DEGA, NIrm);
    normno_kernel<<<(4 * NN + 255) / 256, 256, 0, stream>>>(DEG_SRC, NO);

    // ---- GAT gather (4 graphs fused) ----
    GatArgs ga;
    ga.el[0] = DI;          ga.er[0] = DU + 2 * NU; ga.fsrc[0] = FBI; ga.zout[0] = ZU;
    ga.el[1] = DI + NI;     ga.er[1] = DU + 3 * NU; ga.fsrc[1] = FBI; ga.zout[1] = ZU + 64;
    ga.el[2] = DU;          ga.er[2] = DI + 2 * NI; ga.fsrc[2] = FBU; ga.zout[2] = ZI;
    ga.el[3] = DU + NU;     ga.er[3] = DI + 3 * NI; ga.fsrc[3] = FBU; ga.zout[3] = ZI + 64;
    gat_gather_kernel<<<(4 * NN * 64) / 256, 256, 0, stream>>>(ga, DEGA, ROW, BUCKET);

    // ---- GC gather + transform (4 graphs fused) ----
    GcArgs gc;
    gc.feat[0] = FBU; gc.hout[0] = HU;
    gc.feat[1] = FBU; gc.hout[1] = HU + 64;
    gc.feat[2] = FBI; gc.hout[2] = HI;
    gc.feat[3] = FBI; gc.hout[3] = HI + 64;
    gc_kernel<<<4 * 3125, 256, 0, stream>>>(gc, W_gc, b_gc, NO, NIrm, DEGA, ROW, BUCKET);

    // ---- semantic attentions ----
    sem_att_kernel<<<1024, 256, 0, stream>>>(ZU, sa_rel_W1, sa_rel_b1, sa_rel_w2, WSUM + 0, NU);
    sem_att_kernel<<<1024, 256, 0, stream>>>(ZI, sa_rel_W1, sa_rel_b1, sa_rel_w2, WSUM + 2, NI);
    sem_att_kernel<<<1024, 256, 0, stream>>>(HU, sa_u_W1, sa_u_b1, sa_u_w2, WSUM + 4, NU);
    sem_att_kernel<<<1024, 256, 0, stream>>>(HI, sa_i_W1, sa_i_b1, sa_i_w2, WSUM + 6, NI);

    // ---- combine ----
    combine_kernel<<<((NU + NI) * DD) / 256, 256, 0, stream>>>(ZU, ZI, HU, HI, WSUM, (float*)d_out);
}

// Round 5
// 913.495 us; speedup vs baseline: 2.1638x; 1.0130x over previous
//
#include <hip/hip_runtime.h>
#include <math.h>

#define NU 50000
#define NI 50000
#define NN 50000
#define DD 64
#define HHID 128
#define EE 500000
#define NEG_SLOPE 0.01f
#define NBKT 98            // coarse buckets of 512 nodes (dst>>9)
#define CAP 6144           // capacity per (graph,bucket) coarse region
#define TILE 4096
#define TPG 123            // tiles per graph = ceil(500000/4096)

typedef _Float16 half_t;
union H4 { uint2 u; half_t h[4]; };
union H8 { uint4 u; half_t h[8]; };

struct Ptr4c { const float* p[4]; };
struct Ptr4m { float*       p[4]; };
struct EdgeArgs { const int* src[8]; const int* dst[8]; };
struct GatArgs { const float* el[4]; const float* er[4]; const half_t* fsrc[4]; half_t* zout[4]; };
struct GcArgs  { const half_t* feat[4]; half_t* hout[4]; };
struct SemArgs { const half_t* z[4]; const float* W1[4]; const float* b1[4]; const float* w2[4]; };

// ---------------- fused: fp32 feat -> fp16 table + 4 per-node dots; wave = 4 nodes x 16 lanes
__global__ void dot4_kernel(const float* __restrict__ feat, Ptr4c vecs, Ptr4m outs,
                            half_t* __restrict__ fb16, int n) {
    int gid = blockIdx.x * blockDim.x + threadIdx.x;
    int w = gid >> 6;
    int lane = threadIdx.x & 63;
    int sub = lane >> 4, r = lane & 15;
    int node = w * 4 + sub;
    if (node >= n) return;
    float4 f = *(const float4*)(feat + (size_t)node * DD + r * 4);
    // fp16 table write
    H4 o16;
    o16.h[0] = (half_t)f.x; o16.h[1] = (half_t)f.y; o16.h[2] = (half_t)f.z; o16.h[3] = (half_t)f.w;
    *(uint2*)(fb16 + (size_t)node * DD + r * 4) = o16.u;
#pragma unroll
    for (int j = 0; j < 4; j++) {
        float4 vv = *(const float4*)(vecs.p[j] + r * 4);
        float val = f.x * vv.x + f.y * vv.y + f.z * vv.z + f.w * vv.w;
        val += __shfl_down(val, 8);
        val += __shfl_down(val, 4);
        val += __shfl_down(val, 2);
        val += __shfl_down(val, 1);
        if (r == 0) outs.p[j][node] = val;
    }
}

// ---------------- pass 1: LDS counting-sort partition by dst>>9; packed record src|(dst&511)<<16
__global__ __launch_bounds__(256) void part1_kernel(EdgeArgs a, int* __restrict__ ccnt,
                                                    int* __restrict__ coarse,
                                                    int* __restrict__ deg_src) {
    __shared__ int bc_cnt[128], bc_scan[128], bc_start[128], bc_cur[128], bc_gbase[128];
    __shared__ int stage[TILE];
    __shared__ unsigned char sbkt[TILE];
    int t = threadIdx.x;
    int g = blockIdx.x / TPG;
    int tile = blockIdx.x % TPG;
    int e0 = tile * TILE;
    int tile_n = min(TILE, EE - e0);
    const int* gs = a.src[g];
    const int* gd = a.dst[g];
    if (t < 128) bc_cnt[t] = 0;
    __syncthreads();
    int pw[16]; int pb[16];
#pragma unroll
    for (int i = 0; i < 16; i++) {
        int pos = i * 256 + t;
        pb[i] = -1;
        if (pos < tile_n) {
            int e = e0 + pos;
            int s = gs[e], d = gd[e];
            pw[i] = s | ((d & 511) << 16);
            pb[i] = d >> 9;
            atomicAdd(&bc_cnt[pb[i]], 1);
            if (g >= 4) atomicAdd(&deg_src[(g - 4) * NN + s], 1);
        }
    }
    __syncthreads();
    if (t < 128) bc_scan[t] = bc_cnt[t];
    __syncthreads();
    for (int off = 1; off < 128; off <<= 1) {
        int v = 0;
        if (t < 128 && t >= off) v = bc_scan[t - off];
        __syncthreads();
        if (t < 128) bc_scan[t] += v;
        __syncthreads();
    }
    if (t < 128) {
        int st = bc_scan[t] - bc_cnt[t];
        bc_start[t] = st;
        bc_cur[t] = st;
        bc_gbase[t] = (t < NBKT && bc_cnt[t] > 0) ? atomicAdd(&ccnt[g * NBKT + t], bc_cnt[t]) : 0;
    }
    __syncthreads();
#pragma unroll
    for (int i = 0; i < 16; i++) {
        if (pb[i] >= 0) {
            int slot = atomicAdd(&bc_cur[pb[i]], 1);
            stage[slot] = pw[i];
            sbkt[slot] = (unsigned char)pb[i];
        }
    }
    __syncthreads();
    for (int j = t; j < tile_n; j += 256) {
        int b = sbkt[j];
        int p = stage[j];
        int pos = bc_gbase[b] + (j - bc_start[b]);
        if (pos < CAP) coarse[(size_t)(g * NBKT + b) * CAP + pos] = p;
    }
}

// ---------------- per-graph exclusive scan of coarse bucket counts
__global__ void scanb_kernel(const int* __restrict__ ccnt, int* __restrict__ bktbase) {
    __shared__ int s[128];
    int g = blockIdx.x, t = threadIdx.x;
    int orig = (t < NBKT) ? min(ccnt[g * NBKT + t], CAP) : 0;
    s[t] = orig;
    __syncthreads();
    for (int off = 1; off < 128; off <<= 1) {
        int v = (t >= off) ? s[t - off] : 0;
        __syncthreads();
        s[t] += v;
        __syncthreads();
    }
    if (t < NBKT) bktbase[g * NBKT + t] = s[t] - orig;
}

// ---------------- pass 2: per (graph,bucket) counting sort -> final CSR + row_start + deg + ni
__global__ __launch_bounds__(256) void part2_kernel(const int* __restrict__ ccnt,
                                                    const int* __restrict__ bktbase,
                                                    const int* __restrict__ coarse,
                                                    int* __restrict__ bucket,
                                                    int* __restrict__ row_start,
                                                    int* __restrict__ dega,
                                                    float* __restrict__ nirm) {
    __shared__ int cnt5[512], off5[512], s2[256];
    __shared__ int spairs[CAP];
    __shared__ int ordered[CAP];
    int t = threadIdx.x;
    int g = blockIdx.x / NBKT;
    int b = blockIdx.x % NBKT;
    int n = min(ccnt[g * NBKT + b], CAP);
    int base = bktbase[g * NBKT + b];
    int node0 = b << 9;
    cnt5[t] = 0; cnt5[t + 256] = 0;
    __syncthreads();
    const int* pairs = coarse + (size_t)(g * NBKT + b) * CAP;
    for (int i = t; i < n; i += 256) {
        int p = pairs[i];
        spairs[i] = p;
        atomicAdd(&cnt5[p >> 16], 1);
    }
    __syncthreads();
    int pairsum = cnt5[2 * t] + cnt5[2 * t + 1];
    s2[t] = pairsum;
    __syncthreads();
    for (int off = 1; off < 256; off <<= 1) {
        int v = (t >= off) ? s2[t - off] : 0;
        __syncthreads();
        s2[t] += v;
        __syncthreads();
    }
    int ex = s2[t] - pairsum;
    off5[2 * t] = ex;
    off5[2 * t + 1] = ex + cnt5[2 * t];
    __syncthreads();
#pragma unroll
    for (int k = 0; k < 2; k++) {
        int j = 2 * t + k;
        int v = node0 + j;
        if (v < NN) {
            row_start[g * NN + v] = base + off5[j];
            int d = cnt5[j];
            dega[g * NN + v] = d;
            if (g >= 4) nirm[(g - 4) * NN + v] = (d > 0) ? rsqrtf((float)d) : 1.0f;
        }
    }
    __syncthreads();
    for (int i = t; i < n; i += 256) {
        int p = spairs[i];
        int slot = atomicAdd(&off5[p >> 16], 1);
        ordered[slot] = p & 0xFFFF;
    }
    __syncthreads();
    for (int i = t; i < n; i += 256) bucket[(size_t)g * EE + base + i] = ordered[i];
}

__global__ void normno_kernel(const int* __restrict__ deg_src, float* __restrict__ no) {
    int i = blockIdx.x * blockDim.x + threadIdx.x;
    if (i >= 4 * NN) return;
    int d = deg_src[i];
    no[i] = (d > 0) ? rsqrtf((float)d) : 1.0f;
}

// ---------------- GAT gather: 1 wave = 1 (graph,node); 8 lanes/row, 16 edges in flight
__global__ __launch_bounds__(256) void gat_gather_kernel(GatArgs a, const int* __restrict__ dega,
                                                         const int* __restrict__ row_start,
                                                         const int* __restrict__ bucket) {
    int gid = blockIdx.x * blockDim.x + threadIdx.x;
    int w = gid >> 6, lane = threadIdx.x & 63;
    int g = w / NN, v = w % NN;
    int dg = dega[g * NN + v];
    int start = row_start[g * NN + v];
    const int* bk = bucket + (size_t)g * EE;
    const float* el = a.el[g];
    const half_t* fs = a.fsrc[g];
    float er_v = a.er[g][v];
    int q = lane >> 3, r = lane & 7;
    float acc[8];
#pragma unroll
    for (int i = 0; i < 8; i++) acc[i] = 0.f;
    float s_l = 0.f;
    for (int base = 0; base < dg; base += 16) {
        int e0 = base + q, e1 = base + 8 + q;
        bool b0 = e0 < dg, b1 = e1 < dg;
        int s0 = b0 ? bk[start + e0] : 0;
        int s1 = b1 ? bk[start + e1] : 0;
        float w0 = 0.f, w1 = 0.f;
        if (b0) {
            float e = el[s0] + er_v;
            e = (e >= 0.f) ? e : NEG_SLOPE * e;
            w0 = expf(e);
        }
        if (b1) {
            float e = el[s1] + er_v;
            e = (e >= 0.f) ? e : NEG_SLOPE * e;
            w1 = expf(e);
        }
        s_l += w0 + w1;
        if (b0) {
            H8 row; row.u = *(const uint4*)(fs + (size_t)s0 * DD + r * 8);
#pragma unroll
            for (int i = 0; i < 8; i++) acc[i] += w0 * (float)row.h[i];
        }
        if (b1) {
            H8 row; row.u = *(const uint4*)(fs + (size_t)s1 * DD + r * 8);
#pragma unroll
            for (int i = 0; i < 8; i++) acc[i] += w1 * (float)row.h[i];
        }
    }
    // reduce across the 8 q-groups (each edge counted once per fixed r)
#pragma unroll
    for (int off = 8; off < 64; off <<= 1) {
#pragma unroll
        for (int i = 0; i < 8; i++) acc[i] += __shfl_down(acc[i], off);
        s_l += __shfl_down(s_l, off);
    }
    if (lane < 8) {
        float inv = (dg > 0) ? (1.0f / s_l) : 0.f;
        H8 o;
#pragma unroll
        for (int i = 0; i < 8; i++) {
            float x = acc[i] * inv;
            x = (x > 0.f) ? x : expm1f(x);
            o.h[i] = (half_t)x;
        }
        *(uint4*)(a.zout[g] + (size_t)v * 128 + r * 8) = o.u;
    }
}

// ---------------- GC: 1 wave = 1 node aggregation; 1024-thread block = 16-node transform tile
__global__ __launch_bounds__(1024) void gc_kernel(GcArgs a, const float* __restrict__ W_gc,
                                                  const float* __restrict__ b_gc,
                                                  const float* __restrict__ NO,
                                                  const float* __restrict__ NIrm,
                                                  const int* __restrict__ dega,
                                                  const int* __restrict__ row_start,
                                                  const int* __restrict__ bucket) {
    __shared__ float sW[64 * 64];
    __shared__ float srow[16][64];
    int g = blockIdx.x / 3125;
    int nb = blockIdx.x % 3125;
    int t = threadIdx.x;
    const float* W = W_gc + g * 4096;
    for (int i = t; i < 4096; i += 1024) sW[i] = W[i];
    int wv = t >> 6;              // node slot 0..15
    int lane = t & 63;
    int q = lane >> 3, r = lane & 7;
    const int* bk  = bucket + (size_t)(4 + g) * EE;
    int v = nb * 16 + wv;
    int dg = dega[(4 + g) * NN + v];
    int start = row_start[(4 + g) * NN + v];
    const float* no = NO + g * NN;
    const half_t* feat = a.feat[g];
    float acc[8];
#pragma unroll
    for (int i = 0; i < 8; i++) acc[i] = 0.f;
    for (int base = 0; base < dg; base += 16) {
        int e0 = base + q, e1 = base + 8 + q;
        bool b0 = e0 < dg, b1 = e1 < dg;
        int s0 = b0 ? bk[start + e0] : 0;
        int s1 = b1 ? bk[start + e1] : 0;
        float n0 = b0 ? no[s0] : 0.f;
        float n1 = b1 ? no[s1] : 0.f;
        if (b0) {
            H8 row; row.u = *(const uint4*)(feat + (size_t)s0 * DD + r * 8);
#pragma unroll
            for (int i = 0; i < 8; i++) acc[i] += n0 * (float)row.h[i];
        }
        if (b1) {
            H8 row; row.u = *(const uint4*)(feat + (size_t)s1 * DD + r * 8);
#pragma unroll
            for (int i = 0; i < 8; i++) acc[i] += n1 * (float)row.h[i];
        }
    }
#pragma unroll
    for (int off = 8; off < 64; off <<= 1) {
#pragma unroll
        for (int i = 0; i < 8; i++) acc[i] += __shfl_down(acc[i], off);
    }
    if (lane < 8) {
        float niv = NIrm[g * NN + v];
        *(float4*)(&srow[wv][r * 8])     = make_float4(acc[0] * niv, acc[1] * niv, acc[2] * niv, acc[3] * niv);
        *(float4*)(&srow[wv][r * 8 + 4]) = make_float4(acc[4] * niv, acc[5] * niv, acc[6] * niv, acc[7] * niv);
    }
    __syncthreads();
    // transform: 1024 threads = 16 rows x 64 cols
    int col = lane;
    float accv = 0.f;
#pragma unroll
    for (int k = 0; k < 64; k++) accv += srow[wv][k] * sW[k * 64 + col];
    accv += b_gc[g * 64 + col];
    accv = (accv > 0.f) ? accv : expm1f(accv);
    a.hout[g][(size_t)v * 128 + col] = (half_t)accv;
}

// ---------------- semantic attention (all 4 instances, one launch)
__global__ __launch_bounds__(256) void sem_att_kernel(SemArgs sa, float* __restrict__ wsum) {
    __shared__ float sW1[64 * HHID];
    __shared__ float sb1[HHID];
    __shared__ float sw2[HHID];
    __shared__ float zrow[2][64];
    __shared__ float lsum[2];
    int t = threadIdx.x;
    int inst = blockIdx.x >> 9;          // 512 blocks per instance
    int blk = blockIdx.x & 511;
    const half_t* z = sa.z[inst];
    const float* W1 = sa.W1[inst];
    for (int i = t; i < 64 * HHID; i += 256) sW1[i] = W1[i];
    if (t < HHID) { sb1[t] = sa.b1[inst][t]; sw2[t] = sa.w2[inst][t]; }
    if (t < 2) lsum[t] = 0.f;
    __syncthreads();
    int sub = t >> 7;
    int hh = t & 127;
    const int npairs = 2 * NN;
    for (int p0 = blk * 2; p0 < npairs; p0 += 512 * 2) {
        int p = p0 + sub;
        int nn2 = p >> 1, mm = p & 1;
        __syncthreads();
        if (hh < 16) {
            H8 rr;
            rr.u = *(const uint4*)(z + (size_t)nn2 * 128 + mm * 64 + hh * 8);
#pragma unroll
            for (int i = 0; i < 8; i++) zrow[sub][hh * 8 + i] = (float)rr.h[i];
        }
        __syncthreads();
        {
            float acc = 0.f;
#pragma unroll
            for (int k = 0; k < 64; k++) acc += zrow[sub][k] * sW1[k * HHID + hh];
            float val = tanhf(acc + sb1[hh]) * sw2[hh];
#pragma unroll
            for (int off = 32; off > 0; off >>= 1) val += __shfl_down(val, off);
            if ((t & 63) == 0) atomicAdd(&lsum[mm], val);
        }
    }
    __syncthreads();
    if (t < 2) atomicAdd(&wsum[inst * 2 + t], lsum[t]);
}

// ---------------- final combine: thread = 4 consecutive output cols
__global__ void combine_kernel(const half_t* __restrict__ ZU, const half_t* __restrict__ ZI,
                               const half_t* __restrict__ HU, const half_t* __restrict__ HI,
                               const float* __restrict__ wsum, float* __restrict__ out) {
    int gid = blockIdx.x * blockDim.x + threadIdx.x;
    if (gid >= (NU + NI) * 16) return;
    int node = gid >> 4;
    int c4 = (gid & 15) * 4;
    const half_t* zb; const half_t* hb;
    float wr0, wr1, wh0, wh1;
    int idx;
    if (node < NU) {
        zb = ZU; hb = HU; idx = node;
        wr0 = wsum[0]; wr1 = wsum[1]; wh0 = wsum[4]; wh1 = wsum[5];
    } else {
        zb = ZI; hb = HI; idx = node - NU;
        wr0 = wsum[2]; wr1 = wsum[3]; wh0 = wsum[6]; wh1 = wsum[7];
    }
    const float inv_n = 1.0f / 50000.0f;
    wr0 *= inv_n; wr1 *= inv_n; wh0 *= inv_n; wh1 *= inv_n;
    float m = fmaxf(wr0, wr1);
    float e0 = expf(wr0 - m), e1 = expf(wr1 - m);
    float br0 = e0 / (e0 + e1), br1 = e1 / (e0 + e1);
    m = fmaxf(wh0, wh1);
    e0 = expf(wh0 - m); e1 = expf(wh1 - m);
    float bh0 = e0 / (e0 + e1), bh1 = e1 / (e0 + e1);
    H4 z0, z1, h0, h1;
    z0.u = *(const uint2*)(zb + (size_t)idx * 128 + c4);
    z1.u = *(const uint2*)(zb + (size_t)idx * 128 + 64 + c4);
    h0.u = *(const uint2*)(hb + (size_t)idx * 128 + c4);
    h1.u = *(const uint2*)(hb + (size_t)idx * 128 + 64 + c4);
    float4 o;
    o.x = (float)z0.h[0] * br0 + (float)z1.h[0] * br1 + (float)h0.h[0] * bh0 + (float)h1.h[0] * bh1;
    o.y = (float)z0.h[1] * br0 + (float)z1.h[1] * br1 + (float)h0.h[1] * bh0 + (float)h1.h[1] * bh1;
    o.z = (float)z0.h[2] * br0 + (float)z1.h[2] * br1 + (float)h0.h[2] * bh0 + (float)h1.h[2] * bh1;
    o.w = (float)z0.h[3] * br0 + (float)z1.h[3] * br1 + (float)h0.h[3] * bh0 + (float)h1.h[3] * bh1;
    *(float4*)(out + (size_t)node * 64 + c4) = o;
}

extern "C" void kernel_launch(void* const* d_in, const int* in_sizes, int n_in,
                              void* d_out, int out_size, void* d_ws, size_t ws_size,
                              hipStream_t stream) {
    const float* feat_user = (const float*)d_in[0];
    const float* feat_item = (const float*)d_in[1];
    const float* attn_l    = (const float*)d_in[2];
    const float* attn_r    = (const float*)d_in[3];
    const float* W_gc      = (const float*)d_in[4];
    const float* b_gc      = (const float*)d_in[5];
    const float* sa_rel_W1 = (const float*)d_in[6];
    const float* sa_rel_b1 = (const float*)d_in[7];
    const float* sa_rel_w2 = (const float*)d_in[8];
    const float* sa_u_W1   = (const float*)d_in[9];
    const float* sa_u_b1   = (const float*)d_in[10];
    const float* sa_u_w2   = (const float*)d_in[11];
    const float* sa_i_W1   = (const float*)d_in[12];
    const float* sa_i_b1   = (const float*)d_in[13];
    const float* sa_i_w2   = (const float*)d_in[14];
    const int* rel_u_src = (const int*)d_in[15];
    const int* rel_u_dst = (const int*)d_in[16];
    const int* rel_i_src = (const int*)d_in[17];
    const int* rel_i_dst = (const int*)d_in[18];
    const int* mp_u_src  = (const int*)d_in[19];
    const int* mp_u_dst  = (const int*)d_in[20];
    const int* mp_i_src  = (const int*)d_in[21];
    const int* mp_i_dst  = (const int*)d_in[22];

    // ---- workspace layout ----
    half_t* ZU   = (half_t*)d_ws;             // NN*128 fp16
    half_t* ZI   = ZU + NN * 128;
    half_t* HU   = ZI + NN * 128;
    half_t* HI   = HU + NN * 128;
    half_t* FBU  = HI + NN * 128;             // fp16 feat_user, NN*64
    half_t* FBI  = FBU + NN * 64;             // fp16 feat_item, NN*64
    float*  DI   = (float*)(FBI + NN * 64);   // 4*NN
    float*  DU   = DI + 4 * NN;               // 4*NN
    float*  NO   = DU + 4 * NN;               // 4*NN
    float*  NIrm = NO + 4 * NN;               // 4*NN
    int*    ROW  = (int*)(NIrm + 4 * NN);     // 8*NN
    int*    DEGA = ROW + 8 * NN;              // 8*NN
    int*    BUCKET = DEGA + 8 * NN;           // 8*EE
    int*    BKTBASE = BUCKET + 8 * EE;        // 8*128
    int*    CCNT = BKTBASE + 8 * 128;         // 8*128  -- zeroed
    int*    DEG_SRC = CCNT + 8 * 128;         // 4*NN   -- zeroed
    float*  WSUM = (float*)(DEG_SRC + 4 * NN);// 8      -- zeroed
    int*    COARSE = (int*)d_ws;              // 8*98*CAP ints, aliases ZU..; dead before gathers

    hipMemsetAsync(CCNT, 0, (size_t)(8 * 128 + 4 * NN) * sizeof(int) + 8 * sizeof(float), stream);

    // ---- fused fp16-cvt + dots ----
    Ptr4c vi = {{ attn_l + 0 * DD, attn_l + 1 * DD, attn_r + 2 * DD, attn_r + 3 * DD }};
    Ptr4m oi = {{ DI, DI + NI, DI + 2 * NI, DI + 3 * NI }};
    Ptr4c vu = {{ attn_l + 2 * DD, attn_l + 3 * DD, attn_r + 0 * DD, attn_r + 1 * DD }};
    Ptr4m ou = {{ DU, DU + NU, DU + 2 * NU, DU + 3 * NU }};
    dot4_kernel<<<(NN / 4 * 64) / 256, 256, 0, stream>>>(feat_item, vi, oi, FBI, NI);
    dot4_kernel<<<(NN / 4 * 64) / 256, 256, 0, stream>>>(feat_user, vu, ou, FBU, NU);

    // ---- CSR build ----
    EdgeArgs ea;
    ea.src[0] = rel_u_src;      ea.dst[0] = rel_u_dst;
    ea.src[1] = rel_u_src + EE; ea.dst[1] = rel_u_dst + EE;
    ea.src[2] = rel_i_src;      ea.dst[2] = rel_i_dst;
    ea.src[3] = rel_i_src + EE; ea.dst[3] = rel_i_dst + EE;
    ea.src[4] = mp_u_src;       ea.dst[4] = mp_u_dst;
    ea.src[5] = mp_u_src + EE;  ea.dst[5] = mp_u_dst + EE;
    ea.src[6] = mp_i_src;       ea.dst[6] = mp_i_dst;
    ea.src[7] = mp_i_src + EE;  ea.dst[7] = mp_i_dst + EE;

    part1_kernel<<<8 * TPG, 256, 0, stream>>>(ea, CCNT, COARSE, DEG_SRC);
    scanb_kernel<<<8, 128, 0, stream>>>(CCNT, BKTBASE);
    part2_kernel<<<8 * NBKT, 256, 0, stream>>>(CCNT, BKTBASE, COARSE, BUCKET, ROW, DEGA, NIrm);
    normno_kernel<<<(4 * NN + 255) / 256, 256, 0, stream>>>(DEG_SRC, NO);

    // ---- GAT gather (4 graphs fused) ----
    GatArgs ga;
    ga.el[0] = DI;          ga.er[0] = DU + 2 * NU; ga.fsrc[0] = FBI; ga.zout[0] = ZU;
    ga.el[1] = DI + NI;     ga.er[1] = DU + 3 * NU; ga.fsrc[1] = FBI; ga.zout[1] = ZU + 64;
    ga.el[2] = DU;          ga.er[2] = DI + 2 * NI; ga.fsrc[2] = FBU; ga.zout[2] = ZI;
    ga.el[3] = DU + NU;     ga.er[3] = DI + 3 * NI; ga.fsrc[3] = FBU; ga.zout[3] = ZI + 64;
    gat_gather_kernel<<<(4 * NN * 64) / 256, 256, 0, stream>>>(ga, DEGA, ROW, BUCKET);

    // ---- GC gather + transform (4 graphs fused) ----
    GcArgs gc;
    gc.feat[0] = FBU; gc.hout[0] = HU;
    gc.feat[1] = FBU; gc.hout[1] = HU + 64;
    gc.feat[2] = FBI; gc.hout[2] = HI;
    gc.feat[3] = FBI; gc.hout[3] = HI + 64;
    gc_kernel<<<4 * 3125, 1024, 0, stream>>>(gc, W_gc, b_gc, NO, NIrm, DEGA, ROW, BUCKET);

    // ---- semantic attention (single launch, 4 instances) ----
    SemArgs sa;
    sa.z[0] = ZU; sa.W1[0] = sa_rel_W1; sa.b1[0] = sa_rel_b1; sa.w2[0] = sa_rel_w2;
    sa.z[1] = ZI; sa.W1[1] = sa_rel_W1; sa.b1[1] = sa_rel_b1; sa.w2[1] = sa_rel_w2;
    sa.z[2] = HU; sa.W1[2] = sa_u_W1;   sa.b1[2] = sa_u_b1;   sa.w2[2] = sa_u_w2;
    sa.z[3] = HI; sa.W1[3] = sa_i_W1;   sa.b1[3] = sa_i_b1;   sa.w2[3] = sa_i_w2;
    sem_att_kernel<<<4 * 512, 256, 0, stream>>>(sa, WSUM);

    // ---- combine ----
    combine_kernel<<<((NU + NI) * 16 + 255) / 256, 256, 0, stream>>>(ZU, ZI, HU, HI, WSUM, (float*)d_out);
}

// Round 6
// 883.995 us; speedup vs baseline: 2.2360x; 1.0334x over previous
//
#include <hip/hip_runtime.h>
#include <math.h>

#define NU 50000
#define NI 50000
#define NN 50000
#define DD 64
#define HHID 128
#define EE 500000
#define NEG_SLOPE 0.01f
#define NBKT 98            // coarse buckets of 512 nodes (dst>>9)
#define CAP 6144           // capacity per (graph,bucket) coarse region
#define TILE 4096
#define TPG 123            // tiles per graph = ceil(500000/4096)

typedef _Float16 half_t;
union H4 { uint2 u; half_t h[4]; };
union H8 { uint4 u; half_t h[8]; };

struct Ptr4c { const float* p[4]; };
struct Ptr4m { float*       p[4]; };
struct EdgeArgs { const int* src[8]; const int* dst[8]; };
struct GatArgs { const float* el[4]; const float* er[4]; const half_t* fsrc[4]; half_t* zout[4]; };
struct GcArgs  { const half_t* feat[4]; half_t* hout[4]; };
struct SemArgs { const half_t* z[4]; const float* W1[4]; const float* b1[4]; const float* w2[4]; };

// ---------------- fused: fp32 feat -> fp16 table + 4 per-node dots; wave = 4 nodes x 16 lanes
__global__ void dot4_kernel(const float* __restrict__ feat, Ptr4c vecs, Ptr4m outs,
                            half_t* __restrict__ fb16, int n) {
    int gid = blockIdx.x * blockDim.x + threadIdx.x;
    int w = gid >> 6;
    int lane = threadIdx.x & 63;
    int sub = lane >> 4, r = lane & 15;
    int node = w * 4 + sub;
    if (node >= n) return;
    float4 f = *(const float4*)(feat + (size_t)node * DD + r * 4);
    H4 o16;
    o16.h[0] = (half_t)f.x; o16.h[1] = (half_t)f.y; o16.h[2] = (half_t)f.z; o16.h[3] = (half_t)f.w;
    *(uint2*)(fb16 + (size_t)node * DD + r * 4) = o16.u;
#pragma unroll
    for (int j = 0; j < 4; j++) {
        float4 vv = *(const float4*)(vecs.p[j] + r * 4);
        float val = f.x * vv.x + f.y * vv.y + f.z * vv.z + f.w * vv.w;
        val += __shfl_down(val, 8);
        val += __shfl_down(val, 4);
        val += __shfl_down(val, 2);
        val += __shfl_down(val, 1);
        if (r == 0) outs.p[j][node] = val;
    }
}

// ---------------- pass 1: LDS counting-sort partition by dst>>9; packed record src|(dst&511)<<16
__global__ __launch_bounds__(256) void part1_kernel(EdgeArgs a, int* __restrict__ ccnt,
                                                    int* __restrict__ coarse,
                                                    int* __restrict__ deg_src) {
    __shared__ int bc_cnt[128], bc_scan[128], bc_start[128], bc_cur[128], bc_gbase[128];
    __shared__ int stage[TILE];
    __shared__ unsigned char sbkt[TILE];
    int t = threadIdx.x;
    int g = blockIdx.x / TPG;
    int tile = blockIdx.x % TPG;
    int e0 = tile * TILE;
    int tile_n = min(TILE, EE - e0);
    const int* gs = a.src[g];
    const int* gd = a.dst[g];
    if (t < 128) bc_cnt[t] = 0;
    __syncthreads();
    int pw[16]; int pb[16];
#pragma unroll
    for (int i = 0; i < 16; i++) {
        int pos = i * 256 + t;
        pb[i] = -1;
        if (pos < tile_n) {
            int e = e0 + pos;
            int s = gs[e], d = gd[e];
            pw[i] = s | ((d & 511) << 16);
            pb[i] = d >> 9;
            atomicAdd(&bc_cnt[pb[i]], 1);
            if (g >= 4) atomicAdd(&deg_src[(g - 4) * NN + s], 1);
        }
    }
    __syncthreads();
    if (t < 128) bc_scan[t] = bc_cnt[t];
    __syncthreads();
    for (int off = 1; off < 128; off <<= 1) {
        int v = 0;
        if (t < 128 && t >= off) v = bc_scan[t - off];
        __syncthreads();
        if (t < 128) bc_scan[t] += v;
        __syncthreads();
    }
    if (t < 128) {
        int st = bc_scan[t] - bc_cnt[t];
        bc_start[t] = st;
        bc_cur[t] = st;
        bc_gbase[t] = (t < NBKT && bc_cnt[t] > 0) ? atomicAdd(&ccnt[g * NBKT + t], bc_cnt[t]) : 0;
    }
    __syncthreads();
#pragma unroll
    for (int i = 0; i < 16; i++) {
        if (pb[i] >= 0) {
            int slot = atomicAdd(&bc_cur[pb[i]], 1);
            stage[slot] = pw[i];
            sbkt[slot] = (unsigned char)pb[i];
        }
    }
    __syncthreads();
    for (int j = t; j < tile_n; j += 256) {
        int b = sbkt[j];
        int p = stage[j];
        int pos = bc_gbase[b] + (j - bc_start[b]);
        if (pos < CAP) coarse[(size_t)(g * NBKT + b) * CAP + pos] = p;
    }
}

// ---------------- per-graph exclusive scan of coarse bucket counts
__global__ void scanb_kernel(const int* __restrict__ ccnt, int* __restrict__ bktbase) {
    __shared__ int s[128];
    int g = blockIdx.x, t = threadIdx.x;
    int orig = (t < NBKT) ? min(ccnt[g * NBKT + t], CAP) : 0;
    s[t] = orig;
    __syncthreads();
    for (int off = 1; off < 128; off <<= 1) {
        int v = (t >= off) ? s[t - off] : 0;
        __syncthreads();
        s[t] += v;
        __syncthreads();
    }
    if (t < NBKT) bktbase[g * NBKT + t] = s[t] - orig;
}

// ---------------- pass 2: per (graph,bucket) counting sort -> final CSR + row_start + deg + ni
__global__ __launch_bounds__(256) void part2_kernel(const int* __restrict__ ccnt,
                                                    const int* __restrict__ bktbase,
                                                    const int* __restrict__ coarse,
                                                    int* __restrict__ bucket,
                                                    int* __restrict__ row_start,
                                                    int* __restrict__ dega,
                                                    float* __restrict__ nirm) {
    __shared__ int cnt5[512], off5[512], s2[256];
    __shared__ int spairs[CAP];
    __shared__ int ordered[CAP];
    int t = threadIdx.x;
    int g = blockIdx.x / NBKT;
    int b = blockIdx.x % NBKT;
    int n = min(ccnt[g * NBKT + b], CAP);
    int base = bktbase[g * NBKT + b];
    int node0 = b << 9;
    cnt5[t] = 0; cnt5[t + 256] = 0;
    __syncthreads();
    const int* pairs = coarse + (size_t)(g * NBKT + b) * CAP;
    for (int i = t; i < n; i += 256) {
        int p = pairs[i];
        spairs[i] = p;
        atomicAdd(&cnt5[p >> 16], 1);
    }
    __syncthreads();
    int pairsum = cnt5[2 * t] + cnt5[2 * t + 1];
    s2[t] = pairsum;
    __syncthreads();
    for (int off = 1; off < 256; off <<= 1) {
        int v = (t >= off) ? s2[t - off] : 0;
        __syncthreads();
        s2[t] += v;
        __syncthreads();
    }
    int ex = s2[t] - pairsum;
    off5[2 * t] = ex;
    off5[2 * t + 1] = ex + cnt5[2 * t];
    __syncthreads();
#pragma unroll
    for (int k = 0; k < 2; k++) {
        int j = 2 * t + k;
        int v = node0 + j;
        if (v < NN) {
            row_start[g * NN + v] = base + off5[j];
            int d = cnt5[j];
            dega[g * NN + v] = d;
            if (g >= 4) nirm[(g - 4) * NN + v] = (d > 0) ? rsqrtf((float)d) : 1.0f;
        }
    }
    __syncthreads();
    for (int i = t; i < n; i += 256) {
        int p = spairs[i];
        int slot = atomicAdd(&off5[p >> 16], 1);
        ordered[slot] = p & 0xFFFF;
    }
    __syncthreads();
    for (int i = t; i < n; i += 256) bucket[(size_t)g * EE + base + i] = ordered[i];
}

__global__ void normno_kernel(const int* __restrict__ deg_src, float* __restrict__ no) {
    int i = blockIdx.x * blockDim.x + threadIdx.x;
    if (i >= 4 * NN) return;
    int d = deg_src[i];
    no[i] = (d > 0) ? rsqrtf((float)d) : 1.0f;
}

// ---------------- GAT gather: 1 wave = 1 (graph,node); 8 lanes/row, 16 edges in flight
__global__ __launch_bounds__(256) void gat_gather_kernel(GatArgs a, const int* __restrict__ dega,
                                                         const int* __restrict__ row_start,
                                                         const int* __restrict__ bucket) {
    int gid = blockIdx.x * blockDim.x + threadIdx.x;
    int w = gid >> 6, lane = threadIdx.x & 63;
    int g = w / NN, v = w % NN;
    int dg = dega[g * NN + v];
    int start = row_start[g * NN + v];
    const int* bk = bucket + (size_t)g * EE;
    const float* el = a.el[g];
    const half_t* fs = a.fsrc[g];
    float er_v = a.er[g][v];
    int q = lane >> 3, r = lane & 7;
    float acc[8];
#pragma unroll
    for (int i = 0; i < 8; i++) acc[i] = 0.f;
    float s_l = 0.f;
    for (int base = 0; base < dg; base += 16) {
        int e0 = base + q, e1 = base + 8 + q;
        bool b0 = e0 < dg, b1 = e1 < dg;
        int s0 = b0 ? bk[start + e0] : 0;
        int s1 = b1 ? bk[start + e1] : 0;
        float w0 = 0.f, w1 = 0.f;
        if (b0) {
            float e = el[s0] + er_v;
            e = (e >= 0.f) ? e : NEG_SLOPE * e;
            w0 = expf(e);
        }
        if (b1) {
            float e = el[s1] + er_v;
            e = (e >= 0.f) ? e : NEG_SLOPE * e;
            w1 = expf(e);
        }
        s_l += w0 + w1;
        if (b0) {
            H8 row; row.u = *(const uint4*)(fs + (size_t)s0 * DD + r * 8);
#pragma unroll
            for (int i = 0; i < 8; i++) acc[i] += w0 * (float)row.h[i];
        }
        if (b1) {
            H8 row; row.u = *(const uint4*)(fs + (size_t)s1 * DD + r * 8);
#pragma unroll
            for (int i = 0; i < 8; i++) acc[i] += w1 * (float)row.h[i];
        }
    }
#pragma unroll
    for (int off = 8; off < 64; off <<= 1) {
#pragma unroll
        for (int i = 0; i < 8; i++) acc[i] += __shfl_down(acc[i], off);
        s_l += __shfl_down(s_l, off);
    }
    if (lane < 8) {
        float inv = (dg > 0) ? (1.0f / s_l) : 0.f;
        H8 o;
#pragma unroll
        for (int i = 0; i < 8; i++) {
            float x = acc[i] * inv;
            x = (x > 0.f) ? x : expm1f(x);
            o.h[i] = (half_t)x;
        }
        *(uint4*)(a.zout[g] + (size_t)v * 128 + r * 8) = o.u;
    }
}

// ---------------- GC: 1 wave = 1 node aggregation; 1024-thread block = 16-node transform tile
__global__ __launch_bounds__(1024) void gc_kernel(GcArgs a, const float* __restrict__ W_gc,
                                                  const float* __restrict__ b_gc,
                                                  const float* __restrict__ NO,
                                                  const float* __restrict__ NIrm,
                                                  const int* __restrict__ dega,
                                                  const int* __restrict__ row_start,
                                                  const int* __restrict__ bucket) {
    __shared__ float sW[64 * 64];
    __shared__ float srow[16][64];
    int g = blockIdx.x / 3125;
    int nb = blockIdx.x % 3125;
    int t = threadIdx.x;
    const float* W = W_gc + g * 4096;
    for (int i = t; i < 4096; i += 1024) sW[i] = W[i];
    int wv = t >> 6;
    int lane = t & 63;
    int q = lane >> 3, r = lane & 7;
    const int* bk  = bucket + (size_t)(4 + g) * EE;
    int v = nb * 16 + wv;
    int dg = dega[(4 + g) * NN + v];
    int start = row_start[(4 + g) * NN + v];
    const float* no = NO + g * NN;
    const half_t* feat = a.feat[g];
    float acc[8];
#pragma unroll
    for (int i = 0; i < 8; i++) acc[i] = 0.f;
    for (int base = 0; base < dg; base += 16) {
        int e0 = base + q, e1 = base + 8 + q;
        bool b0 = e0 < dg, b1 = e1 < dg;
        int s0 = b0 ? bk[start + e0] : 0;
        int s1 = b1 ? bk[start + e1] : 0;
        float n0 = b0 ? no[s0] : 0.f;
        float n1 = b1 ? no[s1] : 0.f;
        if (b0) {
            H8 row; row.u = *(const uint4*)(feat + (size_t)s0 * DD + r * 8);
#pragma unroll
            for (int i = 0; i < 8; i++) acc[i] += n0 * (float)row.h[i];
        }
        if (b1) {
            H8 row; row.u = *(const uint4*)(feat + (size_t)s1 * DD + r * 8);
#pragma unroll
            for (int i = 0; i < 8; i++) acc[i] += n1 * (float)row.h[i];
        }
    }
#pragma unroll
    for (int off = 8; off < 64; off <<= 1) {
#pragma unroll
        for (int i = 0; i < 8; i++) acc[i] += __shfl_down(acc[i], off);
    }
    if (lane < 8) {
        float niv = NIrm[g * NN + v];
        *(float4*)(&srow[wv][r * 8])     = make_float4(acc[0] * niv, acc[1] * niv, acc[2] * niv, acc[3] * niv);
        *(float4*)(&srow[wv][r * 8 + 4]) = make_float4(acc[4] * niv, acc[5] * niv, acc[6] * niv, acc[7] * niv);
    }
    __syncthreads();
    int col = lane;
    float accv = 0.f;
#pragma unroll
    for (int k = 0; k < 64; k++) accv += srow[wv][k] * sW[k * 64 + col];
    accv += b_gc[g * 64 + col];
    accv = (accv > 0.f) ? accv : expm1f(accv);
    a.hout[g][(size_t)v * 128 + col] = (half_t)accv;
}

// ---------------- semantic attention: register-resident W1, readlane z broadcast, no LDS
// grid = 4 instances x 256 blocks; wave = 64 lanes; lane owns W1 columns (lane, lane+64)
__global__ __launch_bounds__(256) void sem_att_kernel(SemArgs sa, float* __restrict__ wsum) {
    int inst = blockIdx.x >> 8;        // 256 blocks per instance
    int blk  = blockIdx.x & 255;
    int t = threadIdx.x;
    int wv = t >> 6, lane = t & 63;
    const float* W1 = sa.W1[inst];
    const half_t* z = sa.z[inst];
    float w1a[64], w1b[64];
#pragma unroll
    for (int k = 0; k < 64; k++) {
        w1a[k] = W1[k * HHID + lane];
        w1b[k] = W1[k * HHID + 64 + lane];
    }
    float b1a = sa.b1[inst][lane], b1b = sa.b1[inst][64 + lane];
    float w2a = sa.w2[inst][lane], w2b = sa.w2[inst][64 + lane];
    float local = 0.f;
    int wave_id = blk * 4 + wv;        // 0..1023; stride 1024 keeps pair parity fixed
    const int npairs = 2 * NN;
    for (int p = wave_id; p < npairs; p += 1024) {
        float zl = (float)z[(size_t)(p >> 1) * 128 + (p & 1) * 64 + lane];
        float acc0 = 0.f, acc1 = 0.f;
#pragma unroll
        for (int k = 0; k < 64; k++) {
            float zk = __shfl(zl, k);
            acc0 += zk * w1a[k];
            acc1 += zk * w1b[k];
        }
        float val = tanhf(acc0 + b1a) * w2a + tanhf(acc1 + b1b) * w2b;
#pragma unroll
        for (int off = 32; off > 0; off >>= 1) val += __shfl_down(val, off);
        if (lane == 0) local += val;
    }
    if (lane == 0) atomicAdd(&wsum[inst * 2 + (wave_id & 1)], local);
}

// ---------------- final combine: thread = 4 consecutive output cols
__global__ void combine_kernel(const half_t* __restrict__ ZU, const half_t* __restrict__ ZI,
                               const half_t* __restrict__ HU, const half_t* __restrict__ HI,
                               const float* __restrict__ wsum, float* __restrict__ out) {
    int gid = blockIdx.x * blockDim.x + threadIdx.x;
    if (gid >= (NU + NI) * 16) return;
    int node = gid >> 4;
    int c4 = (gid & 15) * 4;
    const half_t* zb; const half_t* hb;
    float wr0, wr1, wh0, wh1;
    int idx;
    if (node < NU) {
        zb = ZU; hb = HU; idx = node;
        wr0 = wsum[0]; wr1 = wsum[1]; wh0 = wsum[4]; wh1 = wsum[5];
    } else {
        zb = ZI; hb = HI; idx = node - NU;
        wr0 = wsum[2]; wr1 = wsum[3]; wh0 = wsum[6]; wh1 = wsum[7];
    }
    const float inv_n = 1.0f / 50000.0f;
    wr0 *= inv_n; wr1 *= inv_n; wh0 *= inv_n; wh1 *= inv_n;
    float m = fmaxf(wr0, wr1);
    float e0 = expf(wr0 - m), e1 = expf(wr1 - m);
    float br0 = e0 / (e0 + e1), br1 = e1 / (e0 + e1);
    m = fmaxf(wh0, wh1);
    e0 = expf(wh0 - m); e1 = expf(wh1 - m);
    float bh0 = e0 / (e0 + e1), bh1 = e1 / (e0 + e1);
    H4 z0, z1, h0, h1;
    z0.u = *(const uint2*)(zb + (size_t)idx * 128 + c4);
    z1.u = *(const uint2*)(zb + (size_t)idx * 128 + 64 + c4);
    h0.u = *(const uint2*)(hb + (size_t)idx * 128 + c4);
    h1.u = *(const uint2*)(hb + (size_t)idx * 128 + 64 + c4);
    float4 o;
    o.x = (float)z0.h[0] * br0 + (float)z1.h[0] * br1 + (float)h0.h[0] * bh0 + (float)h1.h[0] * bh1;
    o.y = (float)z0.h[1] * br0 + (float)z1.h[1] * br1 + (float)h0.h[1] * bh0 + (float)h1.h[1] * bh1;
    o.z = (float)z0.h[2] * br0 + (float)z1.h[2] * br1 + (float)h0.h[2] * bh0 + (float)h1.h[2] * bh1;
    o.w = (float)z0.h[3] * br0 + (float)z1.h[3] * br1 + (float)h0.h[3] * bh0 + (float)h1.h[3] * bh1;
    *(float4*)(out + (size_t)node * 64 + c4) = o;
}

extern "C" void kernel_launch(void* const* d_in, const int* in_sizes, int n_in,
                              void* d_out, int out_size, void* d_ws, size_t ws_size,
                              hipStream_t stream) {
    const float* feat_user = (const float*)d_in[0];
    const float* feat_item = (const float*)d_in[1];
    const float* attn_l    = (const float*)d_in[2];
    const float* attn_r    = (const float*)d_in[3];
    const float* W_gc      = (const float*)d_in[4];
    const float* b_gc      = (const float*)d_in[5];
    const float* sa_rel_W1 = (const float*)d_in[6];
    const float* sa_rel_b1 = (const float*)d_in[7];
    const float* sa_rel_w2 = (const float*)d_in[8];
    const float* sa_u_W1   = (const float*)d_in[9];
    const float* sa_u_b1   = (const float*)d_in[10];
    const float* sa_u_w2   = (const float*)d_in[11];
    const float* sa_i_W1   = (const float*)d_in[12];
    const float* sa_i_b1   = (const float*)d_in[13];
    const float* sa_i_w2   = (const float*)d_in[14];
    const int* rel_u_src = (const int*)d_in[15];
    const int* rel_u_dst = (const int*)d_in[16];
    const int* rel_i_src = (const int*)d_in[17];
    const int* rel_i_dst = (const int*)d_in[18];
    const int* mp_u_src  = (const int*)d_in[19];
    const int* mp_u_dst  = (const int*)d_in[20];
    const int* mp_i_src  = (const int*)d_in[21];
    const int* mp_i_dst  = (const int*)d_in[22];

    // ---- workspace layout ----
    half_t* ZU   = (half_t*)d_ws;             // NN*128 fp16
    half_t* ZI   = ZU + NN * 128;
    half_t* HU   = ZI + NN * 128;
    half_t* HI   = HU + NN * 128;
    half_t* FBU  = HI + NN * 128;             // fp16 feat_user, NN*64
    half_t* FBI  = FBU + NN * 64;             // fp16 feat_item, NN*64
    float*  DI   = (float*)(FBI + NN * 64);   // 4*NN
    float*  DU   = DI + 4 * NN;               // 4*NN
    float*  NO   = DU + 4 * NN;               // 4*NN
    float*  NIrm = NO + 4 * NN;               // 4*NN
    int*    ROW  = (int*)(NIrm + 4 * NN);     // 8*NN
    int*    DEGA = ROW + 8 * NN;              // 8*NN
    int*    BUCKET = DEGA + 8 * NN;           // 8*EE
    int*    BKTBASE = BUCKET + 8 * EE;        // 8*128
    int*    CCNT = BKTBASE + 8 * 128;         // 8*128  -- zeroed
    int*    DEG_SRC = CCNT + 8 * 128;         // 4*NN   -- zeroed
    float*  WSUM = (float*)(DEG_SRC + 4 * NN);// 8      -- zeroed
    int*    COARSE = (int*)d_ws;              // 8*98*CAP ints, aliases ZU..; dead before gathers

    hipMemsetAsync(CCNT, 0, (size_t)(8 * 128 + 4 * NN) * sizeof(int) + 8 * sizeof(float), stream);

    // ---- fused fp16-cvt + dots ----
    Ptr4c vi = {{ attn_l + 0 * DD, attn_l + 1 * DD, attn_r + 2 * DD, attn_r + 3 * DD }};
    Ptr4m oi = {{ DI, DI + NI, DI + 2 * NI, DI + 3 * NI }};
    Ptr4c vu = {{ attn_l + 2 * DD, attn_l + 3 * DD, attn_r + 0 * DD, attn_r + 1 * DD }};
    Ptr4m ou = {{ DU, DU + NU, DU + 2 * NU, DU + 3 * NU }};
    dot4_kernel<<<(NN / 4 * 64) / 256, 256, 0, stream>>>(feat_item, vi, oi, FBI, NI);
    dot4_kernel<<<(NN / 4 * 64) / 256, 256, 0, stream>>>(feat_user, vu, ou, FBU, NU);

    // ---- CSR build ----
    EdgeArgs ea;
    ea.src[0] = rel_u_src;      ea.dst[0] = rel_u_dst;
    ea.src[1] = rel_u_src + EE; ea.dst[1] = rel_u_dst + EE;
    ea.src[2] = rel_i_src;      ea.dst[2] = rel_i_dst;
    ea.src[3] = rel_i_src + EE; ea.dst[3] = rel_i_dst + EE;
    ea.src[4] = mp_u_src;       ea.dst[4] = mp_u_dst;
    ea.src[5] = mp_u_src + EE;  ea.dst[5] = mp_u_dst + EE;
    ea.src[6] = mp_i_src;       ea.dst[6] = mp_i_dst;
    ea.src[7] = mp_i_src + EE;  ea.dst[7] = mp_i_dst + EE;

    part1_kernel<<<8 * TPG, 256, 0, stream>>>(ea, CCNT, COARSE, DEG_SRC);
    scanb_kernel<<<8, 128, 0, stream>>>(CCNT, BKTBASE);
    part2_kernel<<<8 * NBKT, 256, 0, stream>>>(CCNT, BKTBASE, COARSE, BUCKET, ROW, DEGA, NIrm);
    normno_kernel<<<(4 * NN + 255) / 256, 256, 0, stream>>>(DEG_SRC, NO);

    // ---- GAT gather (4 graphs fused) ----
    GatArgs ga;
    ga.el[0] = DI;          ga.er[0] = DU + 2 * NU; ga.fsrc[0] = FBI; ga.zout[0] = ZU;
    ga.el[1] = DI + NI;     ga.er[1] = DU + 3 * NU; ga.fsrc[1] = FBI; ga.zout[1] = ZU + 64;
    ga.el[2] = DU;          ga.er[2] = DI + 2 * NI; ga.fsrc[2] = FBU; ga.zout[2] = ZI;
    ga.el[3] = DU + NU;     ga.er[3] = DI + 3 * NI; ga.fsrc[3] = FBU; ga.zout[3] = ZI + 64;
    gat_gather_kernel<<<(4 * NN * 64) / 256, 256, 0, stream>>>(ga, DEGA, ROW, BUCKET);

    // ---- GC gather + transform (4 graphs fused) ----
    GcArgs gc;
    gc.feat[0] = FBU; gc.hout[0] = HU;
    gc.feat[1] = FBU; gc.hout[1] = HU + 64;
    gc.feat[2] = FBI; gc.hout[2] = HI;
    gc.feat[3] = FBI; gc.hout[3] = HI + 64;
    gc_kernel<<<4 * 3125, 1024, 0, stream>>>(gc, W_gc, b_gc, NO, NIrm, DEGA, ROW, BUCKET);

    // ---- semantic attention (single launch, 4 instances, register-resident W1) ----
    SemArgs sa;
    sa.z[0] = ZU; sa.W1[0] = sa_rel_W1; sa.b1[0] = sa_rel_b1; sa.w2[0] = sa_rel_w2;
    sa.z[1] = ZI; sa.W1[1] = sa_rel_W1; sa.b1[1] = sa_rel_b1; sa.w2[1] = sa_rel_w2;
    sa.z[2] = HU; sa.W1[2] = sa_u_W1;   sa.b1[2] = sa_u_b1;   sa.w2[2] = sa_u_w2;
    sa.z[3] = HI; sa.W1[3] = sa_i_W1;   sa.b1[3] = sa_i_b1;   sa.w2[3] = sa_i_w2;
    sem_att_kernel<<<4 * 256, 256, 0, stream>>>(sa, WSUM);

    // ---- combine ----
    combine_kernel<<<((NU + NI) * 16 + 255) / 256, 256, 0, stream>>>(ZU, ZI, HU, HI, WSUM, (float*)d_out);
}

// Round 7
// 655.164 us; speedup vs baseline: 3.0170x; 1.3493x over previous
//
#include <hip/hip_runtime.h>
#include <math.h>

#define NU 50000
#define NI 50000
#define NN 50000
#define DD 64
#define HHID 128
#define EE 500000
#define NEG_SLOPE 0.01f
#define NBKT 98            // coarse buckets of 512 nodes (dst>>9)
#define CAP 6144           // capacity per (graph,bucket) coarse region
#define TILE 4096
#define TPG 123            // tiles per graph = ceil(500000/4096)

typedef _Float16 half_t;
typedef _Float16 half8 __attribute__((ext_vector_type(8)));
typedef float f32x4 __attribute__((ext_vector_type(4)));
union H4 { uint2 u; half_t h[4]; };
union H8 { uint4 u; half_t h[8]; };

struct Ptr4c { const float* p[4]; };
struct Ptr4m { float*       p[4]; };
struct EdgeArgs { const int* src[8]; const int* dst[8]; };
struct GatArgs { const float* el[4]; const float* er[4]; const half_t* fsrc[4]; half_t* zout[4]; };
struct GcArgs  { const half_t* feat[4]; half_t* hout[4]; };
struct SemArgs { const half_t* z[4]; const float* W1[4]; const float* b1[4]; const float* w2[4]; };

// ---------------- fused: fp32 feat -> fp16 table + 4 per-node dots; wave = 4 nodes x 16 lanes
__global__ void dot4_kernel(const float* __restrict__ feat, Ptr4c vecs, Ptr4m outs,
                            half_t* __restrict__ fb16, int n) {
    int gid = blockIdx.x * blockDim.x + threadIdx.x;
    int w = gid >> 6;
    int lane = threadIdx.x & 63;
    int sub = lane >> 4, r = lane & 15;
    int node = w * 4 + sub;
    if (node >= n) return;
    float4 f = *(const float4*)(feat + (size_t)node * DD + r * 4);
    H4 o16;
    o16.h[0] = (half_t)f.x; o16.h[1] = (half_t)f.y; o16.h[2] = (half_t)f.z; o16.h[3] = (half_t)f.w;
    *(uint2*)(fb16 + (size_t)node * DD + r * 4) = o16.u;
#pragma unroll
    for (int j = 0; j < 4; j++) {
        float4 vv = *(const float4*)(vecs.p[j] + r * 4);
        float val = f.x * vv.x + f.y * vv.y + f.z * vv.z + f.w * vv.w;
        val += __shfl_down(val, 8);
        val += __shfl_down(val, 4);
        val += __shfl_down(val, 2);
        val += __shfl_down(val, 1);
        if (r == 0) outs.p[j][node] = val;
    }
}

// ---------------- pass 1: LDS counting-sort partition by dst>>9; packed record src|(dst&511)<<16
__global__ __launch_bounds__(256) void part1_kernel(EdgeArgs a, int* __restrict__ ccnt,
                                                    int* __restrict__ coarse,
                                                    int* __restrict__ deg_src) {
    __shared__ int bc_cnt[128], bc_scan[128], bc_start[128], bc_cur[128], bc_gbase[128];
    __shared__ int stage[TILE];
    __shared__ unsigned char sbkt[TILE];
    int t = threadIdx.x;
    int g = blockIdx.x / TPG;
    int tile = blockIdx.x % TPG;
    int e0 = tile * TILE;
    int tile_n = min(TILE, EE - e0);
    const int* gs = a.src[g];
    const int* gd = a.dst[g];
    if (t < 128) bc_cnt[t] = 0;
    __syncthreads();
    int pw[16]; int pb[16];
#pragma unroll
    for (int i = 0; i < 16; i++) {
        int pos = i * 256 + t;
        pb[i] = -1;
        if (pos < tile_n) {
            int e = e0 + pos;
            int s = gs[e], d = gd[e];
            pw[i] = s | ((d & 511) << 16);
            pb[i] = d >> 9;
            atomicAdd(&bc_cnt[pb[i]], 1);
            if (g >= 4) atomicAdd(&deg_src[(g - 4) * NN + s], 1);
        }
    }
    __syncthreads();
    if (t < 128) bc_scan[t] = bc_cnt[t];
    __syncthreads();
    for (int off = 1; off < 128; off <<= 1) {
        int v = 0;
        if (t < 128 && t >= off) v = bc_scan[t - off];
        __syncthreads();
        if (t < 128) bc_scan[t] += v;
        __syncthreads();
    }
    if (t < 128) {
        int st = bc_scan[t] - bc_cnt[t];
        bc_start[t] = st;
        bc_cur[t] = st;
        bc_gbase[t] = (t < NBKT && bc_cnt[t] > 0) ? atomicAdd(&ccnt[g * NBKT + t], bc_cnt[t]) : 0;
    }
    __syncthreads();
#pragma unroll
    for (int i = 0; i < 16; i++) {
        if (pb[i] >= 0) {
            int slot = atomicAdd(&bc_cur[pb[i]], 1);
            stage[slot] = pw[i];
            sbkt[slot] = (unsigned char)pb[i];
        }
    }
    __syncthreads();
    for (int j = t; j < tile_n; j += 256) {
        int b = sbkt[j];
        int p = stage[j];
        int pos = bc_gbase[b] + (j - bc_start[b]);
        if (pos < CAP) coarse[(size_t)(g * NBKT + b) * CAP + pos] = p;
    }
}

// ---------------- per-graph exclusive scan of coarse bucket counts
__global__ void scanb_kernel(const int* __restrict__ ccnt, int* __restrict__ bktbase) {
    __shared__ int s[128];
    int g = blockIdx.x, t = threadIdx.x;
    int orig = (t < NBKT) ? min(ccnt[g * NBKT + t], CAP) : 0;
    s[t] = orig;
    __syncthreads();
    for (int off = 1; off < 128; off <<= 1) {
        int v = (t >= off) ? s[t - off] : 0;
        __syncthreads();
        s[t] += v;
        __syncthreads();
    }
    if (t < NBKT) bktbase[g * NBKT + t] = s[t] - orig;
}

// ---------------- pass 2: per (graph,bucket) counting sort -> final CSR + row_start + deg + ni
__global__ __launch_bounds__(256) void part2_kernel(const int* __restrict__ ccnt,
                                                    const int* __restrict__ bktbase,
                                                    const int* __restrict__ coarse,
                                                    int* __restrict__ bucket,
                                                    int* __restrict__ row_start,
                                                    int* __restrict__ dega,
                                                    float* __restrict__ nirm) {
    __shared__ int cnt5[512], off5[512], s2[256];
    __shared__ int spairs[CAP];
    __shared__ int ordered[CAP];
    int t = threadIdx.x;
    int g = blockIdx.x / NBKT;
    int b = blockIdx.x % NBKT;
    int n = min(ccnt[g * NBKT + b], CAP);
    int base = bktbase[g * NBKT + b];
    int node0 = b << 9;
    cnt5[t] = 0; cnt5[t + 256] = 0;
    __syncthreads();
    const int* pairs = coarse + (size_t)(g * NBKT + b) * CAP;
    for (int i = t; i < n; i += 256) {
        int p = pairs[i];
        spairs[i] = p;
        atomicAdd(&cnt5[p >> 16], 1);
    }
    __syncthreads();
    int pairsum = cnt5[2 * t] + cnt5[2 * t + 1];
    s2[t] = pairsum;
    __syncthreads();
    for (int off = 1; off < 256; off <<= 1) {
        int v = (t >= off) ? s2[t - off] : 0;
        __syncthreads();
        s2[t] += v;
        __syncthreads();
    }
    int ex = s2[t] - pairsum;
    off5[2 * t] = ex;
    off5[2 * t + 1] = ex + cnt5[2 * t];
    __syncthreads();
#pragma unroll
    for (int k = 0; k < 2; k++) {
        int j = 2 * t + k;
        int v = node0 + j;
        if (v < NN) {
            row_start[g * NN + v] = base + off5[j];
            int d = cnt5[j];
            dega[g * NN + v] = d;
            if (g >= 4) nirm[(g - 4) * NN + v] = (d > 0) ? rsqrtf((float)d) : 1.0f;
        }
    }
    __syncthreads();
    for (int i = t; i < n; i += 256) {
        int p = spairs[i];
        int slot = atomicAdd(&off5[p >> 16], 1);
        ordered[slot] = p & 0xFFFF;
    }
    __syncthreads();
    for (int i = t; i < n; i += 256) bucket[(size_t)g * EE + base + i] = ordered[i];
}

__global__ void normno_kernel(const int* __restrict__ deg_src, float* __restrict__ no) {
    int i = blockIdx.x * blockDim.x + threadIdx.x;
    if (i >= 4 * NN) return;
    int d = deg_src[i];
    no[i] = (d > 0) ? rsqrtf((float)d) : 1.0f;
}

// ---------------- GAT gather: 1 wave = 1 (graph,node); 8 lanes/row, 16 edges in flight
__global__ __launch_bounds__(256) void gat_gather_kernel(GatArgs a, const int* __restrict__ dega,
                                                         const int* __restrict__ row_start,
                                                         const int* __restrict__ bucket) {
    int gid = blockIdx.x * blockDim.x + threadIdx.x;
    int w = gid >> 6, lane = threadIdx.x & 63;
    int g = w / NN, v = w % NN;
    int dg = dega[g * NN + v];
    int start = row_start[g * NN + v];
    const int* bk = bucket + (size_t)g * EE;
    const float* el = a.el[g];
    const half_t* fs = a.fsrc[g];
    float er_v = a.er[g][v];
    int q = lane >> 3, r = lane & 7;
    float acc[8];
#pragma unroll
    for (int i = 0; i < 8; i++) acc[i] = 0.f;
    float s_l = 0.f;
    for (int base = 0; base < dg; base += 16) {
        int e0 = base + q, e1 = base + 8 + q;
        bool b0 = e0 < dg, b1 = e1 < dg;
        int s0 = b0 ? bk[start + e0] : 0;
        int s1 = b1 ? bk[start + e1] : 0;
        float w0 = 0.f, w1 = 0.f;
        if (b0) {
            float e = el[s0] + er_v;
            e = (e >= 0.f) ? e : NEG_SLOPE * e;
            w0 = expf(e);
        }
        if (b1) {
            float e = el[s1] + er_v;
            e = (e >= 0.f) ? e : NEG_SLOPE * e;
            w1 = expf(e);
        }
        s_l += w0 + w1;
        if (b0) {
            H8 row; row.u = *(const uint4*)(fs + (size_t)s0 * DD + r * 8);
#pragma unroll
            for (int i = 0; i < 8; i++) acc[i] += w0 * (float)row.h[i];
        }
        if (b1) {
            H8 row; row.u = *(const uint4*)(fs + (size_t)s1 * DD + r * 8);
#pragma unroll
            for (int i = 0; i < 8; i++) acc[i] += w1 * (float)row.h[i];
        }
    }
#pragma unroll
    for (int off = 8; off < 64; off <<= 1) {
#pragma unroll
        for (int i = 0; i < 8; i++) acc[i] += __shfl_down(acc[i], off);
        s_l += __shfl_down(s_l, off);
    }
    if (lane < 8) {
        float inv = (dg > 0) ? (1.0f / s_l) : 0.f;
        H8 o;
#pragma unroll
        for (int i = 0; i < 8; i++) {
            float x = acc[i] * inv;
            x = (x > 0.f) ? x : expm1f(x);
            o.h[i] = (half_t)x;
        }
        *(uint4*)(a.zout[g] + (size_t)v * 128 + r * 8) = o.u;
    }
}

// ---------------- GC: 1 wave = 1 node aggregation; 1024-thread block = 16-node transform tile
__global__ __launch_bounds__(1024) void gc_kernel(GcArgs a, const float* __restrict__ W_gc,
                                                  const float* __restrict__ b_gc,
                                                  const float* __restrict__ NO,
                                                  const float* __restrict__ NIrm,
                                                  const int* __restrict__ dega,
                                                  const int* __restrict__ row_start,
                                                  const int* __restrict__ bucket) {
    __shared__ float sW[64 * 64];
    __shared__ float srow[16][64];
    int g = blockIdx.x / 3125;
    int nb = blockIdx.x % 3125;
    int t = threadIdx.x;
    const float* W = W_gc + g * 4096;
    for (int i = t; i < 4096; i += 1024) sW[i] = W[i];
    int wv = t >> 6;
    int lane = t & 63;
    int q = lane >> 3, r = lane & 7;
    const int* bk  = bucket + (size_t)(4 + g) * EE;
    int v = nb * 16 + wv;
    int dg = dega[(4 + g) * NN + v];
    int start = row_start[(4 + g) * NN + v];
    const float* no = NO + g * NN;
    const half_t* feat = a.feat[g];
    float acc[8];
#pragma unroll
    for (int i = 0; i < 8; i++) acc[i] = 0.f;
    for (int base = 0; base < dg; base += 16) {
        int e0 = base + q, e1 = base + 8 + q;
        bool b0 = e0 < dg, b1 = e1 < dg;
        int s0 = b0 ? bk[start + e0] : 0;
        int s1 = b1 ? bk[start + e1] : 0;
        float n0 = b0 ? no[s0] : 0.f;
        float n1 = b1 ? no[s1] : 0.f;
        if (b0) {
            H8 row; row.u = *(const uint4*)(feat + (size_t)s0 * DD + r * 8);
#pragma unroll
            for (int i = 0; i < 8; i++) acc[i] += n0 * (float)row.h[i];
        }
        if (b1) {
            H8 row; row.u = *(const uint4*)(feat + (size_t)s1 * DD + r * 8);
#pragma unroll
            for (int i = 0; i < 8; i++) acc[i] += n1 * (float)row.h[i];
        }
    }
#pragma unroll
    for (int off = 8; off < 64; off <<= 1) {
#pragma unroll
        for (int i = 0; i < 8; i++) acc[i] += __shfl_down(acc[i], off);
    }
    if (lane < 8) {
        float niv = NIrm[g * NN + v];
        *(float4*)(&srow[wv][r * 8])     = make_float4(acc[0] * niv, acc[1] * niv, acc[2] * niv, acc[3] * niv);
        *(float4*)(&srow[wv][r * 8 + 4]) = make_float4(acc[4] * niv, acc[5] * niv, acc[6] * niv, acc[7] * niv);
    }
    __syncthreads();
    int col = lane;
    float accv = 0.f;
#pragma unroll
    for (int k = 0; k < 64; k++) accv += srow[wv][k] * sW[k * 64 + col];
    accv += b_gc[g * 64 + col];
    accv = (accv > 0.f) ? accv : expm1f(accv);
    a.hout[g][(size_t)v * 128 + col] = (half_t)accv;
}

// ---------------- semantic attention via MFMA: per instance, M=2*NN pairs (16/tile, parity-pure),
// K=64 (2 mfma), N=128 (8 n-tiles). W1 fp16 fragments in registers.
__global__ __launch_bounds__(256) void sem_att_kernel(SemArgs sa, float* __restrict__ wsum) {
    int inst = blockIdx.x >> 8;        // 256 blocks per instance
    int blk  = blockIdx.x & 255;
    int t = threadIdx.x;
    int wv = t >> 6, lane = t & 63;
    int quad = lane >> 4, cl = lane & 15;
    const half_t* z = sa.z[inst];
    const float* W1 = sa.W1[inst];
    // B fragments: B[k][n] with n = cl, k = kh*32 + quad*8 + j
    half8 Bf[8][2];
    float b1v[8], w2v[8];
#pragma unroll
    for (int nt = 0; nt < 8; nt++) {
        int n = nt * 16 + cl;
#pragma unroll
        for (int kh = 0; kh < 2; kh++) {
#pragma unroll
            for (int j = 0; j < 8; j++) {
                int k = kh * 32 + quad * 8 + j;
                Bf[nt][kh][j] = (half_t)W1[k * HHID + n];
            }
        }
        b1v[nt] = sa.b1[inst][n];
        w2v[nt] = sa.w2[inst][n];
    }
    float local0 = 0.f, local1 = 0.f;
    int wave_id = blk * 4 + wv;        // 0..1023
    // 6250 M-tiles: tiles [0,3125) are metapath 0, [3125,6250) metapath 1
    for (int tile = wave_id; tile < 6250; tile += 1024) {
        int m = (tile >= 3125) ? 1 : 0;
        int node = (tile - m * 3125) * 16 + cl;       // A row for this lane
        const half_t* zr = z + (size_t)node * 128 + m * 64 + quad * 8;
        half8 A0 = *(const half8*)(zr);
        half8 A1 = *(const half8*)(zr + 32);
        float sumv = 0.f;
#pragma unroll
        for (int nt = 0; nt < 8; nt++) {
            f32x4 c = {0.f, 0.f, 0.f, 0.f};
            c = __builtin_amdgcn_mfma_f32_16x16x32_f16(A0, Bf[nt][0], c, 0, 0, 0);
            c = __builtin_amdgcn_mfma_f32_16x16x32_f16(A1, Bf[nt][1], c, 0, 0, 0);
#pragma unroll
            for (int r = 0; r < 4; r++) sumv += tanhf(c[r] + b1v[nt]) * w2v[nt];
        }
#pragma unroll
        for (int off = 32; off > 0; off >>= 1) sumv += __shfl_down(sumv, off);
        if (lane == 0) { if (m == 0) local0 += sumv; else local1 += sumv; }
    }
    if (lane == 0) {
        if (local0 != 0.f) atomicAdd(&wsum[inst * 2 + 0], local0);
        if (local1 != 0.f) atomicAdd(&wsum[inst * 2 + 1], local1);
    }
}

// ---------------- final combine: thread = 4 consecutive output cols
__global__ void combine_kernel(const half_t* __restrict__ ZU, const half_t* __restrict__ ZI,
                               const half_t* __restrict__ HU, const half_t* __restrict__ HI,
                               const float* __restrict__ wsum, float* __restrict__ out) {
    int gid = blockIdx.x * blockDim.x + threadIdx.x;
    if (gid >= (NU + NI) * 16) return;
    int node = gid >> 4;
    int c4 = (gid & 15) * 4;
    const half_t* zb; const half_t* hb;
    float wr0, wr1, wh0, wh1;
    int idx;
    if (node < NU) {
        zb = ZU; hb = HU; idx = node;
        wr0 = wsum[0]; wr1 = wsum[1]; wh0 = wsum[4]; wh1 = wsum[5];
    } else {
        zb = ZI; hb = HI; idx = node - NU;
        wr0 = wsum[2]; wr1 = wsum[3]; wh0 = wsum[6]; wh1 = wsum[7];
    }
    const float inv_n = 1.0f / 50000.0f;
    wr0 *= inv_n; wr1 *= inv_n; wh0 *= inv_n; wh1 *= inv_n;
    float m = fmaxf(wr0, wr1);
    float e0 = expf(wr0 - m), e1 = expf(wr1 - m);
    float br0 = e0 / (e0 + e1), br1 = e1 / (e0 + e1);
    m = fmaxf(wh0, wh1);
    e0 = expf(wh0 - m); e1 = expf(wh1 - m);
    float bh0 = e0 / (e0 + e1), bh1 = e1 / (e0 + e1);
    H4 z0, z1, h0, h1;
    z0.u = *(const uint2*)(zb + (size_t)idx * 128 + c4);
    z1.u = *(const uint2*)(zb + (size_t)idx * 128 + 64 + c4);
    h0.u = *(const uint2*)(hb + (size_t)idx * 128 + c4);
    h1.u = *(const uint2*)(hb + (size_t)idx * 128 + 64 + c4);
    float4 o;
    o.x = (float)z0.h[0] * br0 + (float)z1.h[0] * br1 + (float)h0.h[0] * bh0 + (float)h1.h[0] * bh1;
    o.y = (float)z0.h[1] * br0 + (float)z1.h[1] * br1 + (float)h0.h[1] * bh0 + (float)h1.h[1] * bh1;
    o.z = (float)z0.h[2] * br0 + (float)z1.h[2] * br1 + (float)h0.h[2] * bh0 + (float)h1.h[2] * bh1;
    o.w = (float)z0.h[3] * br0 + (float)z1.h[3] * br1 + (float)h0.h[3] * bh0 + (float)h1.h[3] * bh1;
    *(float4*)(out + (size_t)node * 64 + c4) = o;
}

extern "C" void kernel_launch(void* const* d_in, const int* in_sizes, int n_in,
                              void* d_out, int out_size, void* d_ws, size_t ws_size,
                              hipStream_t stream) {
    const float* feat_user = (const float*)d_in[0];
    const float* feat_item = (const float*)d_in[1];
    const float* attn_l    = (const float*)d_in[2];
    const float* attn_r    = (const float*)d_in[3];
    const float* W_gc      = (const float*)d_in[4];
    const float* b_gc      = (const float*)d_in[5];
    const float* sa_rel_W1 = (const float*)d_in[6];
    const float* sa_rel_b1 = (const float*)d_in[7];
    const float* sa_rel_w2 = (const float*)d_in[8];
    const float* sa_u_W1   = (const float*)d_in[9];
    const float* sa_u_b1   = (const float*)d_in[10];
    const float* sa_u_w2   = (const float*)d_in[11];
    const float* sa_i_W1   = (const float*)d_in[12];
    const float* sa_i_b1   = (const float*)d_in[13];
    const float* sa_i_w2   = (const float*)d_in[14];
    const int* rel_u_src = (const int*)d_in[15];
    const int* rel_u_dst = (const int*)d_in[16];
    const int* rel_i_src = (const int*)d_in[17];
    const int* rel_i_dst = (const int*)d_in[18];
    const int* mp_u_src  = (const int*)d_in[19];
    const int* mp_u_dst  = (const int*)d_in[20];
    const int* mp_i_src  = (const int*)d_in[21];
    const int* mp_i_dst  = (const int*)d_in[22];

    // ---- workspace layout ----
    half_t* ZU   = (half_t*)d_ws;             // NN*128 fp16
    half_t* ZI   = ZU + NN * 128;
    half_t* HU   = ZI + NN * 128;
    half_t* HI   = HU + NN * 128;
    half_t* FBU  = HI + NN * 128;             // fp16 feat_user, NN*64
    half_t* FBI  = FBU + NN * 64;             // fp16 feat_item, NN*64
    float*  DI   = (float*)(FBI + NN * 64);   // 4*NN
    float*  DU   = DI + 4 * NN;               // 4*NN
    float*  NO   = DU + 4 * NN;               // 4*NN
    float*  NIrm = NO + 4 * NN;               // 4*NN
    int*    ROW  = (int*)(NIrm + 4 * NN);     // 8*NN
    int*    DEGA = ROW + 8 * NN;              // 8*NN
    int*    BUCKET = DEGA + 8 * NN;           // 8*EE
    int*    BKTBASE = BUCKET + 8 * EE;        // 8*128
    int*    CCNT = BKTBASE + 8 * 128;         // 8*128  -- zeroed
    int*    DEG_SRC = CCNT + 8 * 128;         // 4*NN   -- zeroed
    float*  WSUM = (float*)(DEG_SRC + 4 * NN);// 8      -- zeroed
    int*    COARSE = (int*)d_ws;              // 8*98*CAP ints, aliases ZU..; dead before gathers

    hipMemsetAsync(CCNT, 0, (size_t)(8 * 128 + 4 * NN) * sizeof(int) + 8 * sizeof(float), stream);

    // ---- fused fp16-cvt + dots ----
    Ptr4c vi = {{ attn_l + 0 * DD, attn_l + 1 * DD, attn_r + 2 * DD, attn_r + 3 * DD }};
    Ptr4m oi = {{ DI, DI + NI, DI + 2 * NI, DI + 3 * NI }};
    Ptr4c vu = {{ attn_l + 2 * DD, attn_l + 3 * DD, attn_r + 0 * DD, attn_r + 1 * DD }};
    Ptr4m ou = {{ DU, DU + NU, DU + 2 * NU, DU + 3 * NU }};
    dot4_kernel<<<(NN / 4 * 64) / 256, 256, 0, stream>>>(feat_item, vi, oi, FBI, NI);
    dot4_kernel<<<(NN / 4 * 64) / 256, 256, 0, stream>>>(feat_user, vu, ou, FBU, NU);

    // ---- CSR build ----
    EdgeArgs ea;
    ea.src[0] = rel_u_src;      ea.dst[0] = rel_u_dst;
    ea.src[1] = rel_u_src + EE; ea.dst[1] = rel_u_dst + EE;
    ea.src[2] = rel_i_src;      ea.dst[2] = rel_i_dst;
    ea.src[3] = rel_i_src + EE; ea.dst[3] = rel_i_dst + EE;
    ea.src[4] = mp_u_src;       ea.dst[4] = mp_u_dst;
    ea.src[5] = mp_u_src + EE;  ea.dst[5] = mp_u_dst + EE;
    ea.src[6] = mp_i_src;       ea.dst[6] = mp_i_dst;
    ea.src[7] = mp_i_src + EE;  ea.dst[7] = mp_i_dst + EE;

    part1_kernel<<<8 * TPG, 256, 0, stream>>>(ea, CCNT, COARSE, DEG_SRC);
    scanb_kernel<<<8, 128, 0, stream>>>(CCNT, BKTBASE);
    part2_kernel<<<8 * NBKT, 256, 0, stream>>>(CCNT, BKTBASE, COARSE, BUCKET, ROW, DEGA, NIrm);
    normno_kernel<<<(4 * NN + 255) / 256, 256, 0, stream>>>(DEG_SRC, NO);

    // ---- GAT gather (4 graphs fused) ----
    GatArgs ga;
    ga.el[0] = DI;          ga.er[0] = DU + 2 * NU; ga.fsrc[0] = FBI; ga.zout[0] = ZU;
    ga.el[1] = DI + NI;     ga.er[1] = DU + 3 * NU; ga.fsrc[1] = FBI; ga.zout[1] = ZU + 64;
    ga.el[2] = DU;          ga.er[2] = DI + 2 * NI; ga.fsrc[2] = FBU; ga.zout[2] = ZI;
    ga.el[3] = DU + NU;     ga.er[3] = DI + 3 * NI; ga.fsrc[3] = FBU; ga.zout[3] = ZI + 64;
    gat_gather_kernel<<<(4 * NN * 64) / 256, 256, 0, stream>>>(ga, DEGA, ROW, BUCKET);

    // ---- GC gather + transform (4 graphs fused) ----
    GcArgs gc;
    gc.feat[0] = FBU; gc.hout[0] = HU;
    gc.feat[1] = FBU; gc.hout[1] = HU + 64;
    gc.feat[2] = FBI; gc.hout[2] = HI;
    gc.feat[3] = FBI; gc.hout[3] = HI + 64;
    gc_kernel<<<4 * 3125, 1024, 0, stream>>>(gc, W_gc, b_gc, NO, NIrm, DEGA, ROW, BUCKET);

    // ---- semantic attention (single launch, 4 instances, MFMA) ----
    SemArgs sa;
    sa.z[0] = ZU; sa.W1[0] = sa_rel_W1; sa.b1[0] = sa_rel_b1; sa.w2[0] = sa_rel_w2;
    sa.z[1] = ZI; sa.W1[1] = sa_rel_W1; sa.b1[1] = sa_rel_b1; sa.w2[1] = sa_rel_w2;
    sa.z[2] = HU; sa.W1[2] = sa_u_W1;   sa.b1[2] = sa_u_b1;   sa.w2[2] = sa_u_w2;
    sa.z[3] = HI; sa.W1[3] = sa_i_W1;   sa.b1[3] = sa_i_b1;   sa.w2[3] = sa_i_w2;
    sem_att_kernel<<<4 * 256, 256, 0, stream>>>(sa, WSUM);

    // ---- combine ----
    combine_kernel<<<((NU + NI) * 16 + 255) / 256, 256, 0, stream>>>(ZU, ZI, HU, HI, WSUM, (float*)d_out);
}

// Round 8
// 635.183 us; speedup vs baseline: 3.1119x; 1.0315x over previous
//
#include <hip/hip_runtime.h>
#include <math.h>

#define NU 50000
#define NI 50000
#define NN 50000
#define DD 64
#define HHID 128
#define EE 500000
#define NEG_SLOPE 0.01f
#define NBKT 98            // coarse buckets of 512 nodes (dst>>9)
#define CAP 6144           // capacity per (graph,bucket) coarse region
#define TILE 4096
#define TPG 123            // tiles per graph = ceil(500000/4096)

typedef _Float16 half_t;
typedef _Float16 half8 __attribute__((ext_vector_type(8)));
typedef float f32x4 __attribute__((ext_vector_type(4)));
union H4 { uint2 u; half_t h[4]; };
union H8 { uint4 u; half_t h[8]; };

struct Ptr4c { const float* p[4]; };
struct Ptr4m { float*       p[4]; };
struct EdgeArgs { const int* src[8]; const int* dst[8]; };
struct GatArgs { const float* el[4]; const float* er[4]; const half_t* fsrc[4]; half_t* zout[4]; };
struct GcArgs  { const half_t* feat[4]; half_t* hout[4]; };
struct SemArgs { const half_t* z[4]; const float* W1[4]; const float* b1[4]; const float* w2[4]; };

// ---------------- fused: fp32 feat -> fp16 table + 4 per-node dots; wave = 4 nodes x 16 lanes
__global__ void dot4_kernel(const float* __restrict__ feat, Ptr4c vecs, Ptr4m outs,
                            half_t* __restrict__ fb16, int n) {
    int gid = blockIdx.x * blockDim.x + threadIdx.x;
    int w = gid >> 6;
    int lane = threadIdx.x & 63;
    int sub = lane >> 4, r = lane & 15;
    int node = w * 4 + sub;
    if (node >= n) return;
    float4 f = *(const float4*)(feat + (size_t)node * DD + r * 4);
    H4 o16;
    o16.h[0] = (half_t)f.x; o16.h[1] = (half_t)f.y; o16.h[2] = (half_t)f.z; o16.h[3] = (half_t)f.w;
    *(uint2*)(fb16 + (size_t)node * DD + r * 4) = o16.u;
#pragma unroll
    for (int j = 0; j < 4; j++) {
        float4 vv = *(const float4*)(vecs.p[j] + r * 4);
        float val = f.x * vv.x + f.y * vv.y + f.z * vv.z + f.w * vv.w;
        val += __shfl_down(val, 8);
        val += __shfl_down(val, 4);
        val += __shfl_down(val, 2);
        val += __shfl_down(val, 1);
        if (r == 0) outs.p[j][node] = val;
    }
}

// ---------------- W_gc -> fragment-ordered fp16: W16[((g*8 + nt*2+kh)*64 + lane)*8 + j]
__global__ void prepw_kernel(const float* __restrict__ W_gc, half_t* __restrict__ W16) {
    int g = blockIdx.x;
    int lane = threadIdx.x;
    int cl = lane & 15, quad = lane >> 4;
#pragma unroll
    for (int nt = 0; nt < 4; nt++) {
#pragma unroll
        for (int kh = 0; kh < 2; kh++) {
            H8 o;
#pragma unroll
            for (int j = 0; j < 8; j++) {
                int k = kh * 32 + quad * 8 + j;
                int n = nt * 16 + cl;
                o.h[j] = (half_t)W_gc[g * 4096 + k * 64 + n];
            }
            *(uint4*)(W16 + ((size_t)(g * 8 + nt * 2 + kh) * 64 + lane) * 8) = o.u;
        }
    }
}

// ---------------- pass 1: LDS counting-sort partition by dst>>9; packed record src|(dst&511)<<16
__global__ __launch_bounds__(256) void part1_kernel(EdgeArgs a, int* __restrict__ ccnt,
                                                    int* __restrict__ coarse,
                                                    int* __restrict__ deg_src) {
    __shared__ int bc_cnt[128], bc_scan[128], bc_start[128], bc_cur[128], bc_gbase[128];
    __shared__ int stage[TILE];
    __shared__ unsigned char sbkt[TILE];
    int t = threadIdx.x;
    int g = blockIdx.x / TPG;
    int tile = blockIdx.x % TPG;
    int e0 = tile * TILE;
    int tile_n = min(TILE, EE - e0);
    const int* gs = a.src[g];
    const int* gd = a.dst[g];
    if (t < 128) bc_cnt[t] = 0;
    __syncthreads();
    int pw[16]; int pb[16];
#pragma unroll
    for (int i = 0; i < 16; i++) {
        int pos = i * 256 + t;
        pb[i] = -1;
        if (pos < tile_n) {
            int e = e0 + pos;
            int s = gs[e], d = gd[e];
            pw[i] = s | ((d & 511) << 16);
            pb[i] = d >> 9;
            atomicAdd(&bc_cnt[pb[i]], 1);
            if (g >= 4) atomicAdd(&deg_src[(g - 4) * NN + s], 1);
        }
    }
    __syncthreads();
    if (t < 128) bc_scan[t] = bc_cnt[t];
    __syncthreads();
    for (int off = 1; off < 128; off <<= 1) {
        int v = 0;
        if (t < 128 && t >= off) v = bc_scan[t - off];
        __syncthreads();
        if (t < 128) bc_scan[t] += v;
        __syncthreads();
    }
    if (t < 128) {
        int st = bc_scan[t] - bc_cnt[t];
        bc_start[t] = st;
        bc_cur[t] = st;
        bc_gbase[t] = (t < NBKT && bc_cnt[t] > 0) ? atomicAdd(&ccnt[g * NBKT + t], bc_cnt[t]) : 0;
    }
    __syncthreads();
#pragma unroll
    for (int i = 0; i < 16; i++) {
        if (pb[i] >= 0) {
            int slot = atomicAdd(&bc_cur[pb[i]], 1);
            stage[slot] = pw[i];
            sbkt[slot] = (unsigned char)pb[i];
        }
    }
    __syncthreads();
    for (int j = t; j < tile_n; j += 256) {
        int b = sbkt[j];
        int p = stage[j];
        int pos = bc_gbase[b] + (j - bc_start[b]);
        if (pos < CAP) coarse[(size_t)(g * NBKT + b) * CAP + pos] = p;
    }
}

// ---------------- per-graph exclusive scan of coarse bucket counts
__global__ void scanb_kernel(const int* __restrict__ ccnt, int* __restrict__ bktbase) {
    __shared__ int s[128];
    int g = blockIdx.x, t = threadIdx.x;
    int orig = (t < NBKT) ? min(ccnt[g * NBKT + t], CAP) : 0;
    s[t] = orig;
    __syncthreads();
    for (int off = 1; off < 128; off <<= 1) {
        int v = (t >= off) ? s[t - off] : 0;
        __syncthreads();
        s[t] += v;
        __syncthreads();
    }
    if (t < NBKT) bktbase[g * NBKT + t] = s[t] - orig;
}

// ---------------- pass 2: per (graph,bucket) counting sort -> final CSR + row_start + deg + ni
__global__ __launch_bounds__(256) void part2_kernel(const int* __restrict__ ccnt,
                                                    const int* __restrict__ bktbase,
                                                    const int* __restrict__ coarse,
                                                    int* __restrict__ bucket,
                                                    int* __restrict__ row_start,
                                                    int* __restrict__ dega,
                                                    float* __restrict__ nirm) {
    __shared__ int cnt5[512], off5[512], s2[256];
    __shared__ int spairs[CAP];
    __shared__ int ordered[CAP];
    int t = threadIdx.x;
    int g = blockIdx.x / NBKT;
    int b = blockIdx.x % NBKT;
    int n = min(ccnt[g * NBKT + b], CAP);
    int base = bktbase[g * NBKT + b];
    int node0 = b << 9;
    cnt5[t] = 0; cnt5[t + 256] = 0;
    __syncthreads();
    const int* pairs = coarse + (size_t)(g * NBKT + b) * CAP;
    for (int i = t; i < n; i += 256) {
        int p = pairs[i];
        spairs[i] = p;
        atomicAdd(&cnt5[p >> 16], 1);
    }
    __syncthreads();
    int pairsum = cnt5[2 * t] + cnt5[2 * t + 1];
    s2[t] = pairsum;
    __syncthreads();
    for (int off = 1; off < 256; off <<= 1) {
        int v = (t >= off) ? s2[t - off] : 0;
        __syncthreads();
        s2[t] += v;
        __syncthreads();
    }
    int ex = s2[t] - pairsum;
    off5[2 * t] = ex;
    off5[2 * t + 1] = ex + cnt5[2 * t];
    __syncthreads();
#pragma unroll
    for (int k = 0; k < 2; k++) {
        int j = 2 * t + k;
        int v = node0 + j;
        if (v < NN) {
            row_start[g * NN + v] = base + off5[j];
            int d = cnt5[j];
            dega[g * NN + v] = d;
            if (g >= 4) nirm[(g - 4) * NN + v] = (d > 0) ? rsqrtf((float)d) : 1.0f;
        }
    }
    __syncthreads();
    for (int i = t; i < n; i += 256) {
        int p = spairs[i];
        int slot = atomicAdd(&off5[p >> 16], 1);
        ordered[slot] = p & 0xFFFF;
    }
    __syncthreads();
    for (int i = t; i < n; i += 256) bucket[(size_t)g * EE + base + i] = ordered[i];
}

__global__ void normno_kernel(const int* __restrict__ deg_src, float* __restrict__ no) {
    int i = blockIdx.x * blockDim.x + threadIdx.x;
    if (i >= 4 * NN) return;
    int d = deg_src[i];
    no[i] = (d > 0) ? rsqrtf((float)d) : 1.0f;
}

// ---------------- GAT gather: 1 wave = 1 (graph,node); 8 lanes/row, 16 edges in flight
__global__ __launch_bounds__(256) void gat_gather_kernel(GatArgs a, const int* __restrict__ dega,
                                                         const int* __restrict__ row_start,
                                                         const int* __restrict__ bucket) {
    int gid = blockIdx.x * blockDim.x + threadIdx.x;
    int w = gid >> 6, lane = threadIdx.x & 63;
    int g = w / NN, v = w % NN;
    int dg = dega[g * NN + v];
    int start = row_start[g * NN + v];
    const int* bk = bucket + (size_t)g * EE;
    const float* el = a.el[g];
    const half_t* fs = a.fsrc[g];
    float er_v = a.er[g][v];
    int q = lane >> 3, r = lane & 7;
    float acc[8];
#pragma unroll
    for (int i = 0; i < 8; i++) acc[i] = 0.f;
    float s_l = 0.f;
    for (int base = 0; base < dg; base += 16) {
        int e0 = base + q, e1 = base + 8 + q;
        bool b0 = e0 < dg, b1 = e1 < dg;
        int s0 = b0 ? bk[start + e0] : 0;
        int s1 = b1 ? bk[start + e1] : 0;
        float w0 = 0.f, w1 = 0.f;
        if (b0) {
            float e = el[s0] + er_v;
            e = (e >= 0.f) ? e : NEG_SLOPE * e;
            w0 = expf(e);
        }
        if (b1) {
            float e = el[s1] + er_v;
            e = (e >= 0.f) ? e : NEG_SLOPE * e;
            w1 = expf(e);
        }
        s_l += w0 + w1;
        if (b0) {
            H8 row; row.u = *(const uint4*)(fs + (size_t)s0 * DD + r * 8);
#pragma unroll
            for (int i = 0; i < 8; i++) acc[i] += w0 * (float)row.h[i];
        }
        if (b1) {
            H8 row; row.u = *(const uint4*)(fs + (size_t)s1 * DD + r * 8);
#pragma unroll
            for (int i = 0; i < 8; i++) acc[i] += w1 * (float)row.h[i];
        }
    }
#pragma unroll
    for (int off = 8; off < 64; off <<= 1) {
#pragma unroll
        for (int i = 0; i < 8; i++) acc[i] += __shfl_down(acc[i], off);
        s_l += __shfl_down(s_l, off);
    }
    if (lane < 8) {
        float inv = (dg > 0) ? (1.0f / s_l) : 0.f;
        H8 o;
#pragma unroll
        for (int i = 0; i < 8; i++) {
            float x = acc[i] * inv;
            x = (x > 0.f) ? x : expm1f(x);
            o.h[i] = (half_t)x;
        }
        *(uint4*)(a.zout[g] + (size_t)v * 128 + r * 8) = o.u;
    }
}

// ---------------- GC: 16 waves aggregate 16 nodes -> fp16 LDS tile -> wave 0 MFMA transform
__global__ __launch_bounds__(1024) void gc_kernel(GcArgs a, const half_t* __restrict__ W16,
                                                  const float* __restrict__ b_gc,
                                                  const float* __restrict__ NO,
                                                  const float* __restrict__ NIrm,
                                                  const int* __restrict__ dega,
                                                  const int* __restrict__ row_start,
                                                  const int* __restrict__ bucket) {
    __shared__ half_t srow[16][72];          // +8 halves pad -> 144 B row stride (16B-aligned)
    int g = blockIdx.x / 3125;
    int nb = blockIdx.x % 3125;
    int t = threadIdx.x;
    int wv = t >> 6;
    int lane = t & 63;
    int q = lane >> 3, r = lane & 7;
    const int* bk  = bucket + (size_t)(4 + g) * EE;
    int v = nb * 16 + wv;
    int dg = dega[(4 + g) * NN + v];
    int start = row_start[(4 + g) * NN + v];
    const float* no = NO + g * NN;
    const half_t* feat = a.feat[g];
    float acc[8];
#pragma unroll
    for (int i = 0; i < 8; i++) acc[i] = 0.f;
    for (int base = 0; base < dg; base += 16) {
        int e0 = base + q, e1 = base + 8 + q;
        bool b0 = e0 < dg, b1 = e1 < dg;
        int s0 = b0 ? bk[start + e0] : 0;
        int s1 = b1 ? bk[start + e1] : 0;
        float n0 = b0 ? no[s0] : 0.f;
        float n1 = b1 ? no[s1] : 0.f;
        if (b0) {
            H8 row; row.u = *(const uint4*)(feat + (size_t)s0 * DD + r * 8);
#pragma unroll
            for (int i = 0; i < 8; i++) acc[i] += n0 * (float)row.h[i];
        }
        if (b1) {
            H8 row; row.u = *(const uint4*)(feat + (size_t)s1 * DD + r * 8);
#pragma unroll
            for (int i = 0; i < 8; i++) acc[i] += n1 * (float)row.h[i];
        }
    }
#pragma unroll
    for (int off = 8; off < 64; off <<= 1) {
#pragma unroll
        for (int i = 0; i < 8; i++) acc[i] += __shfl_down(acc[i], off);
    }
    if (lane < 8) {
        float niv = NIrm[g * NN + v];
        H8 o;
#pragma unroll
        for (int i = 0; i < 8; i++) o.h[i] = (half_t)(acc[i] * niv);
        *(uint4*)(&srow[wv][r * 8]) = o.u;
    }
    __syncthreads();
    if (wv == 0) {
        int cl = lane & 15, quad = lane >> 4;
        half8 A0 = *(const half8*)(&srow[cl][quad * 8]);        // k = 0..31
        half8 A1 = *(const half8*)(&srow[cl][32 + quad * 8]);   // k = 32..63
        const half_t* wbase = W16 + (size_t)g * 8 * 64 * 8;
        half_t* hout = a.hout[g];
#pragma unroll
        for (int nt = 0; nt < 4; nt++) {
            float bb = b_gc[g * 64 + nt * 16 + cl];
            f32x4 c = {bb, bb, bb, bb};
            half8 B0 = *(const half8*)(wbase + ((size_t)(nt * 2 + 0) * 64 + lane) * 8);
            half8 B1 = *(const half8*)(wbase + ((size_t)(nt * 2 + 1) * 64 + lane) * 8);
            c = __builtin_amdgcn_mfma_f32_16x16x32_f16(A0, B0, c, 0, 0, 0);
            c = __builtin_amdgcn_mfma_f32_16x16x32_f16(A1, B1, c, 0, 0, 0);
#pragma unroll
            for (int r_ = 0; r_ < 4; r_++) {
                int node = quad * 4 + r_;
                float x = c[r_];
                x = (x > 0.f) ? x : expm1f(x);
                hout[(size_t)(nb * 16 + node) * 128 + nt * 16 + cl] = (half_t)x;
            }
        }
    }
}

// ---------------- semantic attention via MFMA (validated layout)
__global__ __launch_bounds__(256) void sem_att_kernel(SemArgs sa, float* __restrict__ wsum) {
    int inst = blockIdx.x >> 8;
    int blk  = blockIdx.x & 255;
    int t = threadIdx.x;
    int wv = t >> 6, lane = t & 63;
    int quad = lane >> 4, cl = lane & 15;
    const half_t* z = sa.z[inst];
    const float* W1 = sa.W1[inst];
    half8 Bf[8][2];
    float b1v[8], w2v[8];
#pragma unroll
    for (int nt = 0; nt < 8; nt++) {
        int n = nt * 16 + cl;
#pragma unroll
        for (int kh = 0; kh < 2; kh++) {
#pragma unroll
            for (int j = 0; j < 8; j++) {
                int k = kh * 32 + quad * 8 + j;
                Bf[nt][kh][j] = (half_t)W1[k * HHID + n];
            }
        }
        b1v[nt] = sa.b1[inst][n];
        w2v[nt] = sa.w2[inst][n];
    }
    float local0 = 0.f, local1 = 0.f;
    int wave_id = blk * 4 + wv;
    for (int tile = wave_id; tile < 6250; tile += 1024) {
        int m = (tile >= 3125) ? 1 : 0;
        int node = (tile - m * 3125) * 16 + cl;
        const half_t* zr = z + (size_t)node * 128 + m * 64 + quad * 8;
        half8 A0 = *(const half8*)(zr);
        half8 A1 = *(const half8*)(zr + 32);
        float sumv = 0.f;
#pragma unroll
        for (int nt = 0; nt < 8; nt++) {
            f32x4 c = {0.f, 0.f, 0.f, 0.f};
            c = __builtin_amdgcn_mfma_f32_16x16x32_f16(A0, Bf[nt][0], c, 0, 0, 0);
            c = __builtin_amdgcn_mfma_f32_16x16x32_f16(A1, Bf[nt][1], c, 0, 0, 0);
#pragma unroll
            for (int r = 0; r < 4; r++) sumv += tanhf(c[r] + b1v[nt]) * w2v[nt];
        }
#pragma unroll
        for (int off = 32; off > 0; off >>= 1) sumv += __shfl_down(sumv, off);
        if (lane == 0) { if (m == 0) local0 += sumv; else local1 += sumv; }
    }
    if (lane == 0) {
        if (local0 != 0.f) atomicAdd(&wsum[inst * 2 + 0], local0);
        if (local1 != 0.f) atomicAdd(&wsum[inst * 2 + 1], local1);
    }
}

// ---------------- final combine: thread = 4 consecutive output cols
__global__ void combine_kernel(const half_t* __restrict__ ZU, const half_t* __restrict__ ZI,
                               const half_t* __restrict__ HU, const half_t* __restrict__ HI,
                               const float* __restrict__ wsum, float* __restrict__ out) {
    int gid = blockIdx.x * blockDim.x + threadIdx.x;
    if (gid >= (NU + NI) * 16) return;
    int node = gid >> 4;
    int c4 = (gid & 15) * 4;
    const half_t* zb; const half_t* hb;
    float wr0, wr1, wh0, wh1;
    int idx;
    if (node < NU) {
        zb = ZU; hb = HU; idx = node;
        wr0 = wsum[0]; wr1 = wsum[1]; wh0 = wsum[4]; wh1 = wsum[5];
    } else {
        zb = ZI; hb = HI; idx = node - NU;
        wr0 = wsum[2]; wr1 = wsum[3]; wh0 = wsum[6]; wh1 = wsum[7];
    }
    const float inv_n = 1.0f / 50000.0f;
    wr0 *= inv_n; wr1 *= inv_n; wh0 *= inv_n; wh1 *= inv_n;
    float m = fmaxf(wr0, wr1);
    float e0 = expf(wr0 - m), e1 = expf(wr1 - m);
    float br0 = e0 / (e0 + e1), br1 = e1 / (e0 + e1);
    m = fmaxf(wh0, wh1);
    e0 = expf(wh0 - m); e1 = expf(wh1 - m);
    float bh0 = e0 / (e0 + e1), bh1 = e1 / (e0 + e1);
    H4 z0, z1, h0, h1;
    z0.u = *(const uint2*)(zb + (size_t)idx * 128 + c4);
    z1.u = *(const uint2*)(zb + (size_t)idx * 128 + 64 + c4);
    h0.u = *(const uint2*)(hb + (size_t)idx * 128 + c4);
    h1.u = *(const uint2*)(hb + (size_t)idx * 128 + 64 + c4);
    float4 o;
    o.x = (float)z0.h[0] * br0 + (float)z1.h[0] * br1 + (float)h0.h[0] * bh0 + (float)h1.h[0] * bh1;
    o.y = (float)z0.h[1] * br0 + (float)z1.h[1] * br1 + (float)h0.h[1] * bh0 + (float)h1.h[1] * bh1;
    o.z = (float)z0.h[2] * br0 + (float)z1.h[2] * br1 + (float)h0.h[2] * bh0 + (float)h1.h[2] * bh1;
    o.w = (float)z0.h[3] * br0 + (float)z1.h[3] * br1 + (float)h0.h[3] * bh0 + (float)h1.h[3] * bh1;
    *(float4*)(out + (size_t)node * 64 + c4) = o;
}

extern "C" void kernel_launch(void* const* d_in, const int* in_sizes, int n_in,
                              void* d_out, int out_size, void* d_ws, size_t ws_size,
                              hipStream_t stream) {
    const float* feat_user = (const float*)d_in[0];
    const float* feat_item = (const float*)d_in[1];
    const float* attn_l    = (const float*)d_in[2];
    const float* attn_r    = (const float*)d_in[3];
    const float* W_gc      = (const float*)d_in[4];
    const float* b_gc      = (const float*)d_in[5];
    const float* sa_rel_W1 = (const float*)d_in[6];
    const float* sa_rel_b1 = (const float*)d_in[7];
    const float* sa_rel_w2 = (const float*)d_in[8];
    const float* sa_u_W1   = (const float*)d_in[9];
    const float* sa_u_b1   = (const float*)d_in[10];
    const float* sa_u_w2   = (const float*)d_in[11];
    const float* sa_i_W1   = (const float*)d_in[12];
    const float* sa_i_b1   = (const float*)d_in[13];
    const float* sa_i_w2   = (const float*)d_in[14];
    const int* rel_u_src = (const int*)d_in[15];
    const int* rel_u_dst = (const int*)d_in[16];
    const int* rel_i_src = (const int*)d_in[17];
    const int* rel_i_dst = (const int*)d_in[18];
    const int* mp_u_src  = (const int*)d_in[19];
    const int* mp_u_dst  = (const int*)d_in[20];
    const int* mp_i_src  = (const int*)d_in[21];
    const int* mp_i_dst  = (const int*)d_in[22];

    // ---- workspace layout ----
    half_t* ZU   = (half_t*)d_ws;             // NN*128 fp16
    half_t* ZI   = ZU + NN * 128;
    half_t* HU   = ZI + NN * 128;
    half_t* HI   = HU + NN * 128;
    half_t* FBU  = HI + NN * 128;             // fp16 feat_user, NN*64
    half_t* FBI  = FBU + NN * 64;             // fp16 feat_item, NN*64
    float*  DI   = (float*)(FBI + NN * 64);   // 4*NN
    float*  DU   = DI + 4 * NN;               // 4*NN
    float*  NO   = DU + 4 * NN;               // 4*NN
    float*  NIrm = NO + 4 * NN;               // 4*NN
    int*    ROW  = (int*)(NIrm + 4 * NN);     // 8*NN
    int*    DEGA = ROW + 8 * NN;              // 8*NN
    int*    BUCKET = DEGA + 8 * NN;           // 8*EE
    int*    BKTBASE = BUCKET + 8 * EE;        // 8*128
    int*    CCNT = BKTBASE + 8 * 128;         // 8*128  -- zeroed
    int*    DEG_SRC = CCNT + 8 * 128;         // 4*NN   -- zeroed
    float*  WSUM = (float*)(DEG_SRC + 4 * NN);// 8      -- zeroed
    half_t* W16  = (half_t*)(WSUM + 8);       // 4*4096 fp16 fragment-ordered W
    int*    COARSE = (int*)d_ws;              // 8*98*CAP ints, aliases ZU..; dead before gathers

    hipMemsetAsync(CCNT, 0, (size_t)(8 * 128 + 4 * NN) * sizeof(int) + 8 * sizeof(float), stream);

    // ---- W fragment prep + fused fp16-cvt + dots ----
    prepw_kernel<<<4, 64, 0, stream>>>(W_gc, W16);
    Ptr4c vi = {{ attn_l + 0 * DD, attn_l + 1 * DD, attn_r + 2 * DD, attn_r + 3 * DD }};
    Ptr4m oi = {{ DI, DI + NI, DI + 2 * NI, DI + 3 * NI }};
    Ptr4c vu = {{ attn_l + 2 * DD, attn_l + 3 * DD, attn_r + 0 * DD, attn_r + 1 * DD }};
    Ptr4m ou = {{ DU, DU + NU, DU + 2 * NU, DU + 3 * NU }};
    dot4_kernel<<<(NN / 4 * 64) / 256, 256, 0, stream>>>(feat_item, vi, oi, FBI, NI);
    dot4_kernel<<<(NN / 4 * 64) / 256, 256, 0, stream>>>(feat_user, vu, ou, FBU, NU);

    // ---- CSR build ----
    EdgeArgs ea;
    ea.src[0] = rel_u_src;      ea.dst[0] = rel_u_dst;
    ea.src[1] = rel_u_src + EE; ea.dst[1] = rel_u_dst + EE;
    ea.src[2] = rel_i_src;      ea.dst[2] = rel_i_dst;
    ea.src[3] = rel_i_src + EE; ea.dst[3] = rel_i_dst + EE;
    ea.src[4] = mp_u_src;       ea.dst[4] = mp_u_dst;
    ea.src[5] = mp_u_src + EE;  ea.dst[5] = mp_u_dst + EE;
    ea.src[6] = mp_i_src;       ea.dst[6] = mp_i_dst;
    ea.src[7] = mp_i_src + EE;  ea.dst[7] = mp_i_dst + EE;

    part1_kernel<<<8 * TPG, 256, 0, stream>>>(ea, CCNT, COARSE, DEG_SRC);
    scanb_kernel<<<8, 128, 0, stream>>>(CCNT, BKTBASE);
    part2_kernel<<<8 * NBKT, 256, 0, stream>>>(CCNT, BKTBASE, COARSE, BUCKET, ROW, DEGA, NIrm);
    normno_kernel<<<(4 * NN + 255) / 256, 256, 0, stream>>>(DEG_SRC, NO);

    // ---- GAT gather (4 graphs fused) ----
    GatArgs ga;
    ga.el[0] = DI;          ga.er[0] = DU + 2 * NU; ga.fsrc[0] = FBI; ga.zout[0] = ZU;
    ga.el[1] = DI + NI;     ga.er[1] = DU + 3 * NU; ga.fsrc[1] = FBI; ga.zout[1] = ZU + 64;
    ga.el[2] = DU;          ga.er[2] = DI + 2 * NI; ga.fsrc[2] = FBU; ga.zout[2] = ZI;
    ga.el[3] = DU + NU;     ga.er[3] = DI + 3 * NI; ga.fsrc[3] = FBU; ga.zout[3] = ZI + 64;
    gat_gather_kernel<<<(4 * NN * 64) / 256, 256, 0, stream>>>(ga, DEGA, ROW, BUCKET);

    // ---- GC gather + MFMA transform (4 graphs fused) ----
    GcArgs gc;
    gc.feat[0] = FBU; gc.hout[0] = HU;
    gc.feat[1] = FBU; gc.hout[1] = HU + 64;
    gc.feat[2] = FBI; gc.hout[2] = HI;
    gc.feat[3] = FBI; gc.hout[3] = HI + 64;
    gc_kernel<<<4 * 3125, 1024, 0, stream>>>(gc, W16, b_gc, NO, NIrm, DEGA, ROW, BUCKET);

    // ---- semantic attention (single launch, 4 instances, MFMA) ----
    SemArgs sa;
    sa.z[0] = ZU; sa.W1[0] = sa_rel_W1; sa.b1[0] = sa_rel_b1; sa.w2[0] = sa_rel_w2;
    sa.z[1] = ZI; sa.W1[1] = sa_rel_W1; sa.b1[1] = sa_rel_b1; sa.w2[1] = sa_rel_w2;
    sa.z[2] = HU; sa.W1[2] = sa_u_W1;   sa.b1[2] = sa_u_b1;   sa.w2[2] = sa_u_w2;
    sa.z[3] = HI; sa.W1[3] = sa_i_W1;   sa.b1[3] = sa_i_b1;   sa.w2[3] = sa_i_w2;
    sem_att_kernel<<<4 * 256, 256, 0, stream>>>(sa, WSUM);

    // ---- combine ----
    combine_kernel<<<((NU + NI) * 16 + 255) / 256, 256, 0, stream>>>(ZU, ZI, HU, HI, WSUM, (float*)d_out);
}